// Round 1
// baseline (824.641 us; speedup 1.0000x reference)
//
#include <hip/hip_runtime.h>
#include <hip/hip_bf16.h>
#include <math.h>

typedef __hip_bfloat16 bf16;
typedef __attribute__((ext_vector_type(8))) short short8;
typedef __attribute__((ext_vector_type(4))) short short4v;
typedef __attribute__((ext_vector_type(4))) float f32x4;

#define DEV static __device__ __forceinline__

DEV short f2bf(float f) {
    bf16 h = __float2bfloat16(f);
    return __builtin_bit_cast(short, h);
}

DEV void glds16(const void* g, void* l) {
    __builtin_amdgcn_global_load_lds((const __attribute__((address_space(1))) void*)g,
                                     (__attribute__((address_space(3))) void*)l, 16, 0, 0);
}

// ---------------------------------------------------------------- cast f32->bf16
__global__ __launch_bounds__(256) void cast_kernel(const float* __restrict__ src,
                                                   bf16* __restrict__ dst, int n4) {
    int i = blockIdx.x * blockDim.x + threadIdx.x;
    if (i < n4) {
        f32x4 v = ((const f32x4*)src)[i];
        short4v o;
        #pragma unroll
        for (int j = 0; j < 4; j++) o[j] = f2bf(v[j]);
        ((short4v*)dst)[i] = o;
    }
}

// ---------------------------------------------------------------- BN eval affine precompute
__global__ __launch_bounds__(256) void affine_kernel(const float* __restrict__ g,
                                                     const float* __restrict__ b,
                                                     const float* __restrict__ m,
                                                     const float* __restrict__ v,
                                                     float* __restrict__ s,
                                                     float* __restrict__ t, int n) {
    int i = blockIdx.x * blockDim.x + threadIdx.x;
    if (i < n) {
        float sc = g[i] * rsqrtf(v[i] + 1e-5f);
        s[i] = sc;
        t[i] = b[i] - m[i] * sc;
    }
}

// ---------------------------------------------------------------- LayerNorm (row=1024) + optional raw cast
__global__ __launch_bounds__(256) void ln_kernel(const float* __restrict__ x,
                                                 const float* __restrict__ g,
                                                 const float* __restrict__ b,
                                                 bf16* __restrict__ lnout,
                                                 bf16* __restrict__ rawout) {
    const int row = blockIdx.x, t = threadIdx.x;
    const float* xr = x + (size_t)row * 1024;
    f32x4 v = ((const f32x4*)xr)[t];
    float s = v[0] + v[1] + v[2] + v[3];
    float sq = v[0]*v[0] + v[1]*v[1] + v[2]*v[2] + v[3]*v[3];
    #pragma unroll
    for (int off = 1; off < 64; off <<= 1) {
        s  += __shfl_xor(s, off);
        sq += __shfl_xor(sq, off);
    }
    __shared__ float ls[4], lq[4];
    if ((t & 63) == 0) { ls[t >> 6] = s; lq[t >> 6] = sq; }
    __syncthreads();
    s = ls[0] + ls[1] + ls[2] + ls[3];
    sq = lq[0] + lq[1] + lq[2] + lq[3];
    float mu = s * (1.0f / 1024.0f);
    float rs = rsqrtf(sq * (1.0f / 1024.0f) - mu * mu + 1e-5f);
    f32x4 gg = ((const f32x4*)g)[t];
    f32x4 bb = ((const f32x4*)b)[t];
    short4v o;
    #pragma unroll
    for (int j = 0; j < 4; j++) o[j] = f2bf((v[j] - mu) * rs * gg[j] + bb[j]);
    ((short4v*)(lnout + (size_t)row * 1024))[t] = o;
    if (rawout) {
        short4v r;
        #pragma unroll
        for (int j = 0; j < 4; j++) r[j] = f2bf(v[j]);
        ((short4v*)(rawout + (size_t)row * 1024))[t] = r;
    }
}

// ---------------------------------------------------------------- GEMM: C = A[M,K] @ B[N,K]^T (+bias), epilogue variants
enum { M_BF16 = 0, M_VT = 1, M_RESBN = 2, M_GELU = 3 };

template <int MODE>
__global__ __launch_bounds__(256) void gemm_kernel(
    const bf16* __restrict__ A, const bf16* __restrict__ Bw, const float* __restrict__ bias,
    void* __restrict__ out, const float* __restrict__ res,
    const float* __restrict__ sa, const float* __restrict__ ta,
    int N, int K, float scale) {
    __shared__ bf16 As[128 * 32];
    __shared__ bf16 Bs[128 * 32];
    const int tid = threadIdx.x, lane = tid & 63, wid = tid >> 6;
    const int bm = blockIdx.y << 7, bn = blockIdx.x << 7;
    const int wm = (wid >> 1) << 6, wn = (wid & 1) << 6;
    f32x4 acc[4][4] = {};
    // staging: tile 128x32 bf16 = 8KB, 2 issues of 4KB; per wave 1KB (16 rows x 64B)
    const int strow = (wid << 4) + (lane >> 2);
    const int stcol = (lane & 3) << 3;
    const bf16* ag0 = A + (size_t)(bm + strow) * K + stcol;
    const bf16* ag1 = A + (size_t)(bm + 64 + strow) * K + stcol;
    const bf16* bg0 = Bw + (size_t)(bn + strow) * K + stcol;
    const bf16* bg1 = Bw + (size_t)(bn + 64 + strow) * K + stcol;
    bf16* la0 = As + (wid << 9);
    bf16* la1 = As + 2048 + (wid << 9);
    bf16* lb0 = Bs + (wid << 9);
    bf16* lb1 = Bs + 2048 + (wid << 9);
    const int arow = lane & 15, koff = (lane >> 4) << 3;

    for (int kb = 0; kb < K; kb += 32) {
        glds16(ag0 + kb, la0);
        glds16(ag1 + kb, la1);
        glds16(bg0 + kb, lb0);
        glds16(bg1 + kb, lb1);
        __syncthreads();
        short8 af[4], bfr[4];
        #pragma unroll
        for (int m = 0; m < 4; m++)
            af[m] = *(const short8*)(As + ((wm + (m << 4) + arow) << 5) + koff);
        #pragma unroll
        for (int n = 0; n < 4; n++)
            bfr[n] = *(const short8*)(Bs + ((wn + (n << 4) + arow) << 5) + koff);
        #pragma unroll
        for (int m = 0; m < 4; m++)
            #pragma unroll
            for (int n = 0; n < 4; n++)
                acc[m][n] = __builtin_amdgcn_mfma_f32_16x16x32_bf16(af[m], bfr[n], acc[m][n], 0, 0, 0);
        __syncthreads();
    }

    #pragma unroll
    for (int m = 0; m < 4; m++) {
        #pragma unroll
        for (int n = 0; n < 4; n++) {
            const int col = bn + wn + (n << 4) + arow;
            const float bv = bias[col];
            #pragma unroll
            for (int j = 0; j < 4; j++) {
                const int row = bm + wm + (m << 4) + ((lane >> 4) << 2) + j;
                float v = acc[m][n][j] + bv;
                if constexpr (MODE == M_BF16) {
                    ((bf16*)out)[(size_t)row * N + col] = __float2bfloat16(v * scale);
                } else if constexpr (MODE == M_VT) {
                    // row = b*1024+s ; dest vT[b][col][s]
                    ((bf16*)out)[((size_t)(row >> 10) << 20) + ((size_t)col << 10) + (row & 1023)] =
                        __float2bfloat16(v);
                } else if constexpr (MODE == M_RESBN) {
                    size_t idx = (size_t)row * N + col;
                    ((float*)out)[idx] = (res[idx] + v) * sa[col] + ta[col];
                } else {  // M_GELU
                    float ge = 0.5f * v * (1.0f + erff(v * 0.70710678118f));
                    ((bf16*)out)[(size_t)row * N + col] = __float2bfloat16(ge * sa[col] + ta[col]);
                }
            }
        }
    }
}

// ---------------------------------------------------------------- fused scores+mask+softmax -> attn (f32)
// block: 32 q-rows x 1024 k-cols, 4 waves each own 256 cols; scores stay in registers
__global__ __launch_bounds__(256) void attn_kernel(const bf16* __restrict__ q,
                                                   const bf16* __restrict__ k,
                                                   const int* __restrict__ mask,
                                                   float* __restrict__ attn) {
    const int bh = blockIdx.y, b = bh >> 4, h = bh & 15;
    const int q0 = blockIdx.x << 5;
    const int tid = threadIdx.x, lane = tid & 63, wid = tid >> 6;
    const int cb = wid << 8;
    const int arow = lane & 15, koff = (lane >> 4) << 3;

    short8 qf[2];
    #pragma unroll
    for (int m = 0; m < 2; m++)
        qf[m] = *(const short8*)(q + ((size_t)((b << 10) + q0 + (m << 4) + arow) << 10) + (h << 6) + koff);

    f32x4 acc[2][16];
    #pragma unroll
    for (int m = 0; m < 2; m++)
        #pragma unroll
        for (int n = 0; n < 16; n++) acc[m][n] = (f32x4){0.f, 0.f, 0.f, 0.f};

    #pragma unroll
    for (int n = 0; n < 16; n++) {
        short8 kf = *(const short8*)(k + ((size_t)((b << 10) + cb + (n << 4) + arow) << 10) + (h << 6) + koff);
        acc[0][n] = __builtin_amdgcn_mfma_f32_16x16x32_bf16(qf[0], kf, acc[0][n], 0, 0, 0);
        acc[1][n] = __builtin_amdgcn_mfma_f32_16x16x32_bf16(qf[1], kf, acc[1][n], 0, 0, 0);
    }

    float rmax[2][4];
    #pragma unroll
    for (int m = 0; m < 2; m++)
        #pragma unroll
        for (int j = 0; j < 4; j++) rmax[m][j] = -3.0e38f;

    #pragma unroll
    for (int n = 0; n < 16; n++) {
        const float madd = mask[(b << 10) + cb + (n << 4) + arow] ? 0.0f : -1e9f;
        #pragma unroll
        for (int m = 0; m < 2; m++)
            #pragma unroll
            for (int j = 0; j < 4; j++) {
                acc[m][n][j] += madd;
                rmax[m][j] = fmaxf(rmax[m][j], acc[m][n][j]);
            }
    }
    #pragma unroll
    for (int off = 1; off < 16; off <<= 1)
        #pragma unroll
        for (int m = 0; m < 2; m++)
            #pragma unroll
            for (int j = 0; j < 4; j++) rmax[m][j] = fmaxf(rmax[m][j], __shfl_xor(rmax[m][j], off));

    __shared__ float red[2][4][32];
    const int rbase = (lane >> 4) << 2;
    if ((lane & 15) == 0) {
        #pragma unroll
        for (int m = 0; m < 2; m++)
            #pragma unroll
            for (int j = 0; j < 4; j++) red[0][wid][(m << 4) + rbase + j] = rmax[m][j];
    }
    __syncthreads();
    #pragma unroll
    for (int m = 0; m < 2; m++)
        #pragma unroll
        for (int j = 0; j < 4; j++) {
            int r = (m << 4) + rbase + j;
            rmax[m][j] = fmaxf(fmaxf(red[0][0][r], red[0][1][r]), fmaxf(red[0][2][r], red[0][3][r]));
        }

    float rsum[2][4] = {};
    #pragma unroll
    for (int n = 0; n < 16; n++)
        #pragma unroll
        for (int m = 0; m < 2; m++)
            #pragma unroll
            for (int j = 0; j < 4; j++) {
                float p = __expf(acc[m][n][j] - rmax[m][j]);
                acc[m][n][j] = p;
                rsum[m][j] += p;
            }
    #pragma unroll
    for (int off = 1; off < 16; off <<= 1)
        #pragma unroll
        for (int m = 0; m < 2; m++)
            #pragma unroll
            for (int j = 0; j < 4; j++) rsum[m][j] += __shfl_xor(rsum[m][j], off);

    if ((lane & 15) == 0) {
        #pragma unroll
        for (int m = 0; m < 2; m++)
            #pragma unroll
            for (int j = 0; j < 4; j++) red[1][wid][(m << 4) + rbase + j] = rsum[m][j];
    }
    __syncthreads();
    #pragma unroll
    for (int m = 0; m < 2; m++)
        #pragma unroll
        for (int j = 0; j < 4; j++) {
            int r = (m << 4) + rbase + j;
            rsum[m][j] = 1.0f / (red[1][0][r] + red[1][1][r] + red[1][2][r] + red[1][3][r]);
        }

    const size_t obase = (((size_t)bh << 10) + q0) << 10;
    #pragma unroll
    for (int m = 0; m < 2; m++)
        #pragma unroll
        for (int j = 0; j < 4; j++) {
            float* orow = attn + obase + ((size_t)((m << 4) + rbase + j) << 10) + cb;
            float inv = rsum[m][j];
            #pragma unroll
            for (int n = 0; n < 16; n++) orow[(n << 4) + arow] = acc[m][n][j] * inv;
        }
}

// ---------------------------------------------------------------- context = attn @ V  (vT layout: [b][h*64+dk][s])
__global__ __launch_bounds__(256) void pv_kernel(const float* __restrict__ attn,
                                                 const bf16* __restrict__ vT,
                                                 bf16* __restrict__ ctx) {
    const int bh = blockIdx.y, b = bh >> 4, h = bh & 15;
    const int bm = blockIdx.x << 7;
    __shared__ bf16 As[128 * 32];
    __shared__ bf16 Bs[64 * 32];
    const int tid = threadIdx.x, lane = tid & 63, wid = tid >> 6;
    const int wm = (wid >> 1) << 6, wn = (wid & 1) << 5;
    f32x4 acc[4][2] = {};
    const int arow = lane & 15, koff = (lane >> 4) << 3;
    const size_t abase = (((size_t)bh << 10) + bm) << 10;
    const bf16* vbase = vT + ((size_t)((b << 10) + (h << 6) + (wid << 4) + (lane >> 2)) << 10) + ((lane & 3) << 3);
    bf16* lb = Bs + (wid << 9);
    const int ar = tid >> 1, ac = (tid & 1) << 4;
    const float* asrc = attn + abase + (size_t)ar * 1024 + ac;
    bf16* adst = As + (ar << 5) + ac;

    for (int kb = 0; kb < 1024; kb += 32) {
        glds16(vbase + kb, lb);
        f32x4 v0 = *(const f32x4*)(asrc + kb);
        f32x4 v1 = *(const f32x4*)(asrc + kb + 4);
        f32x4 v2 = *(const f32x4*)(asrc + kb + 8);
        f32x4 v3 = *(const f32x4*)(asrc + kb + 12);
        short8 o0, o1;
        o0[0] = f2bf(v0[0]); o0[1] = f2bf(v0[1]); o0[2] = f2bf(v0[2]); o0[3] = f2bf(v0[3]);
        o0[4] = f2bf(v1[0]); o0[5] = f2bf(v1[1]); o0[6] = f2bf(v1[2]); o0[7] = f2bf(v1[3]);
        o1[0] = f2bf(v2[0]); o1[1] = f2bf(v2[1]); o1[2] = f2bf(v2[2]); o1[3] = f2bf(v2[3]);
        o1[4] = f2bf(v3[0]); o1[5] = f2bf(v3[1]); o1[6] = f2bf(v3[2]); o1[7] = f2bf(v3[3]);
        *(short8*)adst = o0;
        *(short8*)(adst + 8) = o1;
        __syncthreads();
        short8 af[4], bfr[2];
        #pragma unroll
        for (int m = 0; m < 4; m++)
            af[m] = *(const short8*)(As + ((wm + (m << 4) + arow) << 5) + koff);
        #pragma unroll
        for (int n = 0; n < 2; n++)
            bfr[n] = *(const short8*)(Bs + ((wn + (n << 4) + arow) << 5) + koff);
        #pragma unroll
        for (int m = 0; m < 4; m++)
            #pragma unroll
            for (int n = 0; n < 2; n++)
                acc[m][n] = __builtin_amdgcn_mfma_f32_16x16x32_bf16(af[m], bfr[n], acc[m][n], 0, 0, 0);
        __syncthreads();
    }

    #pragma unroll
    for (int m = 0; m < 4; m++)
        #pragma unroll
        for (int n = 0; n < 2; n++)
            #pragma unroll
            for (int j = 0; j < 4; j++) {
                int row = bm + wm + (m << 4) + ((lane >> 4) << 2) + j;   // s
                int col = (h << 6) + wn + (n << 4) + arow;               // feature
                ctx[((size_t)((b << 10) + row) << 10) + col] = __float2bfloat16(acc[m][n][j]);
            }
}

// ---------------------------------------------------------------- launch
extern "C" void kernel_launch(void* const* d_in, const int* in_sizes, int n_in,
                              void* d_out, int out_size, void* d_ws, size_t ws_size,
                              hipStream_t stream) {
    (void)in_sizes; (void)n_in; (void)out_size; (void)ws_size;
    const float* x   = (const float*)d_in[0];
    const int*   mask= (const int*)d_in[1];
    const float* Wq  = (const float*)d_in[2];  const float* bq  = (const float*)d_in[3];
    const float* Wk  = (const float*)d_in[4];  const float* bk  = (const float*)d_in[5];
    const float* Wv  = (const float*)d_in[6];  const float* bv  = (const float*)d_in[7];
    const float* Wo  = (const float*)d_in[8];  const float* bo  = (const float*)d_in[9];
    const float* lag = (const float*)d_in[10]; const float* lab = (const float*)d_in[11];
    const float* W1  = (const float*)d_in[12]; const float* b1  = (const float*)d_in[13];
    const float* W2  = (const float*)d_in[14]; const float* b2  = (const float*)d_in[15];
    const float* lfg = (const float*)d_in[16]; const float* lfb = (const float*)d_in[17];
    const float* bffg= (const float*)d_in[18]; const float* bffb= (const float*)d_in[19];
    const float* bffm= (const float*)d_in[20]; const float* bffv= (const float*)d_in[21];
    const float* b1g = (const float*)d_in[22]; const float* b1b = (const float*)d_in[23];
    const float* b1m = (const float*)d_in[24]; const float* b1v = (const float*)d_in[25];
    const float* b2g = (const float*)d_in[26]; const float* b2b = (const float*)d_in[27];
    const float* b2m = (const float*)d_in[28]; const float* b2v = (const float*)d_in[29];

    char* ws = (char*)d_ws;
    const size_t MB = 1024 * 1024;
    bf16* wq_bf = (bf16*)(ws);
    bf16* wk_bf = (bf16*)(ws + 2 * MB);
    bf16* wv_bf = (bf16*)(ws + 4 * MB);
    bf16* wo_bf = (bf16*)(ws + 6 * MB);
    bf16* w1_bf = (bf16*)(ws + 8 * MB);
    bf16* w2_bf = (bf16*)(ws + 16 * MB);
    float* s1  = (float*)(ws + 24 * MB); float* t1  = s1 + 1024;
    float* s2  = t1 + 1024;              float* t2  = s2 + 1024;
    float* sff = t2 + 1024;              float* tff = sff + 4096;
    bf16* x_bf   = (bf16*)(ws + 25 * MB);
    bf16* xq_bf  = (bf16*)(ws + 41 * MB);
    bf16* q_bf   = (bf16*)(ws + 57 * MB);
    bf16* k_bf   = (bf16*)(ws + 73 * MB);
    bf16* vT_bf  = (bf16*)(ws + 89 * MB);
    bf16* ctx_bf = (bf16*)(ws + 105 * MB);
    float* x1    = (float*)(ws + 121 * MB);
    bf16* xn_bf  = (bf16*)(ws + 153 * MB);
    bf16* h_bf   = (bf16*)(ws + 169 * MB);   // 64 MB, ends at 233 MB

    float* out_x    = (float*)d_out;
    float* out_attn = out_x + (size_t)8 * 1024 * 1024;

    // weights -> bf16 ; BN affines
    cast_kernel<<<1024, 256, 0, stream>>>(Wq, wq_bf, 262144);
    cast_kernel<<<1024, 256, 0, stream>>>(Wk, wk_bf, 262144);
    cast_kernel<<<1024, 256, 0, stream>>>(Wv, wv_bf, 262144);
    cast_kernel<<<1024, 256, 0, stream>>>(Wo, wo_bf, 262144);
    cast_kernel<<<4096, 256, 0, stream>>>(W1, w1_bf, 1048576);
    cast_kernel<<<4096, 256, 0, stream>>>(W2, w2_bf, 1048576);
    affine_kernel<<<4, 256, 0, stream>>>(b1g, b1b, b1m, b1v, s1, t1, 1024);
    affine_kernel<<<4, 256, 0, stream>>>(b2g, b2b, b2m, b2v, s2, t2, 1024);
    affine_kernel<<<16, 256, 0, stream>>>(bffg, bffb, bffm, bffv, sff, tff, 4096);

    // LN(x) (for q) + raw cast (for k,v)
    ln_kernel<<<8192, 256, 0, stream>>>(x, lag, lab, xq_bf, x_bf);

    dim3 g1024(8, 64), gw1(32, 64);
    // q = (LN(x)@Wq^T + bq)/8 ; k = x@Wk^T + bk ; v transposed-store
    gemm_kernel<M_BF16><<<g1024, 256, 0, stream>>>(xq_bf, wq_bf, bq, q_bf, nullptr, nullptr, nullptr, 1024, 1024, 0.125f);
    gemm_kernel<M_BF16><<<g1024, 256, 0, stream>>>(x_bf, wk_bf, bk, k_bf, nullptr, nullptr, nullptr, 1024, 1024, 1.0f);
    gemm_kernel<M_VT><<<g1024, 256, 0, stream>>>(x_bf, wv_bf, bv, vT_bf, nullptr, nullptr, nullptr, 1024, 1024, 1.0f);

    // attention: scores+mask+softmax -> attn (d_out), then context = attn@V
    attn_kernel<<<dim3(32, 128), 256, 0, stream>>>(q_bf, k_bf, mask, out_attn);
    pv_kernel<<<dim3(8, 128), 256, 0, stream>>>(out_attn, vT_bf, ctx_bf);

    // attn_out proj + residual + bn1 -> x1 (f32)
    gemm_kernel<M_RESBN><<<g1024, 256, 0, stream>>>(ctx_bf, wo_bf, bo, x1, x, s1, t1, 1024, 1024, 1.0f);

    // FFN: LN -> W1+gelu+bnff -> W2 + residual + bn2 -> d_out
    ln_kernel<<<8192, 256, 0, stream>>>(x1, lfg, lfb, xn_bf, nullptr);
    gemm_kernel<M_GELU><<<gw1, 256, 0, stream>>>(xn_bf, w1_bf, b1, h_bf, nullptr, sff, tff, 4096, 1024, 1.0f);
    gemm_kernel<M_RESBN><<<g1024, 256, 0, stream>>>(h_bf, w2_bf, b2, out_x, x1, s2, t2, 1024, 4096, 1.0f);
}

// Round 2
// 737.129 us; speedup vs baseline: 1.1187x; 1.1187x over previous
//
#include <hip/hip_runtime.h>
#include <hip/hip_bf16.h>
#include <math.h>

typedef __hip_bfloat16 bf16;
typedef __attribute__((ext_vector_type(8))) short short8;
typedef __attribute__((ext_vector_type(4))) short short4v;
typedef __attribute__((ext_vector_type(4))) float f32x4;

#define DEV static __device__ __forceinline__

DEV short f2bf(float f) {
    bf16 h = __float2bfloat16(f);
    return __builtin_bit_cast(short, h);
}

DEV void glds16(const void* g, void* l) {
    __builtin_amdgcn_global_load_lds((const __attribute__((address_space(1))) void*)g,
                                     (__attribute__((address_space(3))) void*)l, 16, 0, 0);
}

// ---------------------------------------------------------------- all weight casts in one kernel
// regions (f32x4 units): wqkv [0,786432) from Wq|Wk|Wv, wo [786432,1048576),
//                        w1 [1048576,2097152), w2 [2097152,3145728)
__global__ __launch_bounds__(256) void cast_all(const float* __restrict__ Wq,
                                                const float* __restrict__ Wk,
                                                const float* __restrict__ Wv,
                                                const float* __restrict__ Wo,
                                                const float* __restrict__ W1,
                                                const float* __restrict__ W2,
                                                bf16* __restrict__ wqkv, bf16* __restrict__ wo,
                                                bf16* __restrict__ w1, bf16* __restrict__ w2) {
    int i = blockIdx.x * 256 + threadIdx.x;
    const float* src;
    bf16* dst;
    int si, di;
    if (i < 786432) {
        src = (i < 262144) ? Wq : (i < 524288) ? Wk : Wv;
        si = (i < 262144) ? i : (i < 524288) ? i - 262144 : i - 524288;
        dst = wqkv; di = i;
    } else if (i < 1048576) {
        src = Wo; si = i - 786432; dst = wo; di = si;
    } else if (i < 2097152) {
        src = W1; si = i - 1048576; dst = w1; di = si;
    } else {
        src = W2; si = i - 2097152; dst = w2; di = si;
    }
    f32x4 v = ((const f32x4*)src)[si];
    short4v o;
    #pragma unroll
    for (int j = 0; j < 4; j++) o[j] = f2bf(v[j]);
    ((short4v*)dst)[di] = o;
}

// ---------------------------------------------------------------- BN eval affines (bn1, bn2, bnff)
__global__ __launch_bounds__(256) void affine_all(
    const float* __restrict__ g1, const float* __restrict__ bb1, const float* __restrict__ m1, const float* __restrict__ v1,
    const float* __restrict__ g2, const float* __restrict__ bb2, const float* __restrict__ m2, const float* __restrict__ v2,
    const float* __restrict__ gf, const float* __restrict__ bbf, const float* __restrict__ mf, const float* __restrict__ vf,
    float* __restrict__ s1, float* __restrict__ t1, float* __restrict__ s2, float* __restrict__ t2,
    float* __restrict__ sf, float* __restrict__ tf) {
    int i = blockIdx.x * 256 + threadIdx.x;
    const float *g, *b, *m, *v; float *s, *t; int j;
    if (i < 1024)      { g = g1; b = bb1; m = m1; v = v1; s = s1; t = t1; j = i; }
    else if (i < 2048) { g = g2; b = bb2; m = m2; v = v2; s = s2; t = t2; j = i - 1024; }
    else               { g = gf; b = bbf; m = mf; v = vf; s = sf; t = tf; j = i - 2048; }
    float sc = g[j] * rsqrtf(v[j] + 1e-5f);
    s[j] = sc;
    t[j] = b[j] - m[j] * sc;
}

// ---------------------------------------------------------------- LayerNorm (row=1024) + optional raw cast
__global__ __launch_bounds__(256) void ln_kernel(const float* __restrict__ x,
                                                 const float* __restrict__ g,
                                                 const float* __restrict__ b,
                                                 bf16* __restrict__ lnout,
                                                 bf16* __restrict__ rawout) {
    const int row = blockIdx.x, t = threadIdx.x;
    const float* xr = x + (size_t)row * 1024;
    f32x4 v = ((const f32x4*)xr)[t];
    float s = v[0] + v[1] + v[2] + v[3];
    float sq = v[0]*v[0] + v[1]*v[1] + v[2]*v[2] + v[3]*v[3];
    #pragma unroll
    for (int off = 1; off < 64; off <<= 1) {
        s  += __shfl_xor(s, off);
        sq += __shfl_xor(sq, off);
    }
    __shared__ float ls[4], lq[4];
    if ((t & 63) == 0) { ls[t >> 6] = s; lq[t >> 6] = sq; }
    __syncthreads();
    s = ls[0] + ls[1] + ls[2] + ls[3];
    sq = lq[0] + lq[1] + lq[2] + lq[3];
    float mu = s * (1.0f / 1024.0f);
    float rs = rsqrtf(sq * (1.0f / 1024.0f) - mu * mu + 1e-5f);
    f32x4 gg = ((const f32x4*)g)[t];
    f32x4 bb = ((const f32x4*)b)[t];
    short4v o;
    #pragma unroll
    for (int j = 0; j < 4; j++) o[j] = f2bf((v[j] - mu) * rs * gg[j] + bb[j]);
    ((short4v*)(lnout + (size_t)row * 1024))[t] = o;
    if (rawout) {
        short4v r;
        #pragma unroll
        for (int j = 0; j < 4; j++) r[j] = f2bf(v[j]);
        ((short4v*)(rawout + (size_t)row * 1024))[t] = r;
    }
}

// ---------------------------------------------------------------- QKV projection: A depends on col region
__global__ __launch_bounds__(256) void gemm_qkv(
    const bf16* __restrict__ Aln, const bf16* __restrict__ Araw, const bf16* __restrict__ Bw,
    const float* __restrict__ bq, const float* __restrict__ bk, const float* __restrict__ bv,
    bf16* __restrict__ qo, bf16* __restrict__ ko, bf16* __restrict__ vTo) {
    __shared__ bf16 As[128 * 32];
    __shared__ bf16 Bs[128 * 32];
    const int tid = threadIdx.x, lane = tid & 63, wid = tid >> 6;
    const int bm = blockIdx.y << 7, bn = blockIdx.x << 7;
    const bf16* A = (bn < 1024) ? Aln : Araw;
    const int wm = (wid >> 1) << 6, wn = (wid & 1) << 6;
    f32x4 acc[4][4] = {};
    const int strow = (wid << 4) + (lane >> 2);
    const int stcol = (lane & 3) << 3;
    const bf16* ag0 = A + (size_t)(bm + strow) * 1024 + stcol;
    const bf16* ag1 = A + (size_t)(bm + 64 + strow) * 1024 + stcol;
    const bf16* bg0 = Bw + (size_t)(bn + strow) * 1024 + stcol;
    const bf16* bg1 = Bw + (size_t)(bn + 64 + strow) * 1024 + stcol;
    bf16* la0 = As + (wid << 9);
    bf16* la1 = As + 2048 + (wid << 9);
    bf16* lb0 = Bs + (wid << 9);
    bf16* lb1 = Bs + 2048 + (wid << 9);
    const int arow = lane & 15, koff = (lane >> 4) << 3;

    for (int kb = 0; kb < 1024; kb += 32) {
        glds16(ag0 + kb, la0);
        glds16(ag1 + kb, la1);
        glds16(bg0 + kb, lb0);
        glds16(bg1 + kb, lb1);
        __syncthreads();
        short8 af[4], bfr[4];
        #pragma unroll
        for (int m = 0; m < 4; m++)
            af[m] = *(const short8*)(As + ((wm + (m << 4) + arow) << 5) + koff);
        #pragma unroll
        for (int n = 0; n < 4; n++)
            bfr[n] = *(const short8*)(Bs + ((wn + (n << 4) + arow) << 5) + koff);
        #pragma unroll
        for (int m = 0; m < 4; m++)
            #pragma unroll
            for (int n = 0; n < 4; n++)
                acc[m][n] = __builtin_amdgcn_mfma_f32_16x16x32_bf16(af[m], bfr[n], acc[m][n], 0, 0, 0);
        __syncthreads();
    }

    #pragma unroll
    for (int m = 0; m < 4; m++) {
        #pragma unroll
        for (int n = 0; n < 4; n++) {
            const int col = bn + wn + (n << 4) + arow;
            const int reg = col >> 10, c = col & 1023;
            const float bvv = (reg == 0) ? bq[c] : (reg == 1) ? bk[c] : bv[c];
            #pragma unroll
            for (int j = 0; j < 4; j++) {
                const int row = bm + wm + (m << 4) + ((lane >> 4) << 2) + j;
                float v = acc[m][n][j] + bvv;
                if (reg == 0)
                    qo[(size_t)row * 1024 + c] = __float2bfloat16(v * 0.125f);
                else if (reg == 1)
                    ko[(size_t)row * 1024 + c] = __float2bfloat16(v);
                else
                    vTo[((size_t)(row >> 10) << 20) + ((size_t)c << 10) + (row & 1023)] =
                        __float2bfloat16(v);
            }
        }
    }
}

// ---------------------------------------------------------------- generic GEMM epilogues
enum { M_RESBN = 0, M_GELU = 1 };

template <int MODE>
__global__ __launch_bounds__(256) void gemm_kernel(
    const bf16* __restrict__ A, const bf16* __restrict__ Bw, const float* __restrict__ bias,
    void* __restrict__ out, const float* __restrict__ res,
    const float* __restrict__ sa, const float* __restrict__ ta,
    int N, int K) {
    __shared__ bf16 As[128 * 32];
    __shared__ bf16 Bs[128 * 32];
    const int tid = threadIdx.x, lane = tid & 63, wid = tid >> 6;
    const int bm = blockIdx.y << 7, bn = blockIdx.x << 7;
    const int wm = (wid >> 1) << 6, wn = (wid & 1) << 6;
    f32x4 acc[4][4] = {};
    const int strow = (wid << 4) + (lane >> 2);
    const int stcol = (lane & 3) << 3;
    const bf16* ag0 = A + (size_t)(bm + strow) * K + stcol;
    const bf16* ag1 = A + (size_t)(bm + 64 + strow) * K + stcol;
    const bf16* bg0 = Bw + (size_t)(bn + strow) * K + stcol;
    const bf16* bg1 = Bw + (size_t)(bn + 64 + strow) * K + stcol;
    bf16* la0 = As + (wid << 9);
    bf16* la1 = As + 2048 + (wid << 9);
    bf16* lb0 = Bs + (wid << 9);
    bf16* lb1 = Bs + 2048 + (wid << 9);
    const int arow = lane & 15, koff = (lane >> 4) << 3;

    for (int kb = 0; kb < K; kb += 32) {
        glds16(ag0 + kb, la0);
        glds16(ag1 + kb, la1);
        glds16(bg0 + kb, lb0);
        glds16(bg1 + kb, lb1);
        __syncthreads();
        short8 af[4], bfr[4];
        #pragma unroll
        for (int m = 0; m < 4; m++)
            af[m] = *(const short8*)(As + ((wm + (m << 4) + arow) << 5) + koff);
        #pragma unroll
        for (int n = 0; n < 4; n++)
            bfr[n] = *(const short8*)(Bs + ((wn + (n << 4) + arow) << 5) + koff);
        #pragma unroll
        for (int m = 0; m < 4; m++)
            #pragma unroll
            for (int n = 0; n < 4; n++)
                acc[m][n] = __builtin_amdgcn_mfma_f32_16x16x32_bf16(af[m], bfr[n], acc[m][n], 0, 0, 0);
        __syncthreads();
    }

    #pragma unroll
    for (int m = 0; m < 4; m++) {
        #pragma unroll
        for (int n = 0; n < 4; n++) {
            const int col = bn + wn + (n << 4) + arow;
            const float bv = bias[col];
            #pragma unroll
            for (int j = 0; j < 4; j++) {
                const int row = bm + wm + (m << 4) + ((lane >> 4) << 2) + j;
                float v = acc[m][n][j] + bv;
                if constexpr (MODE == M_RESBN) {
                    size_t idx = (size_t)row * N + col;
                    ((float*)out)[idx] = (res[idx] + v) * sa[col] + ta[col];
                } else {  // M_GELU
                    float ge = 0.5f * v * (1.0f + erff(v * 0.70710678118f));
                    ((bf16*)out)[(size_t)row * N + col] = __float2bfloat16(ge * sa[col] + ta[col]);
                }
            }
        }
    }
}

// ---------------------------------------------------------------- fused scores+softmax+attn-write+PV
// block: 32 q-rows x 1024 k-cols; wave w owns k-cols [w*256, w*256+256)
// smem reuse: red (1KB, softmax) -> per-wave P tiles [4][32][256] bf16 (64KB) -> ctx partials [4][32][72] f32
__global__ __launch_bounds__(256) void fattn_kernel(const bf16* __restrict__ q,
                                                    const bf16* __restrict__ k,
                                                    const bf16* __restrict__ vT,
                                                    const int* __restrict__ mask,
                                                    float* __restrict__ attn,
                                                    bf16* __restrict__ ctx) {
    const int bh = blockIdx.y, b = bh >> 4, h = bh & 15;
    const int q0 = blockIdx.x << 5;
    const int tid = threadIdx.x, lane = tid & 63, wid = tid >> 6;
    const int cb = wid << 8;
    const int arow = lane & 15, hi = lane >> 4, koff = hi << 3;
    const int rbase = hi << 2;

    __shared__ char smem[65536];
    float* red = (float*)smem;   // [2][4][32]

    // ---- QK^T ----
    short8 qf[2];
    #pragma unroll
    for (int m = 0; m < 2; m++)
        qf[m] = *(const short8*)(q + ((size_t)((b << 10) + q0 + (m << 4) + arow) << 10) + (h << 6) + koff);

    f32x4 acc[2][16];
    #pragma unroll
    for (int m = 0; m < 2; m++)
        #pragma unroll
        for (int n = 0; n < 16; n++) acc[m][n] = (f32x4){0.f, 0.f, 0.f, 0.f};

    #pragma unroll
    for (int n = 0; n < 16; n++) {
        short8 kf = *(const short8*)(k + ((size_t)((b << 10) + cb + (n << 4) + arow) << 10) + (h << 6) + koff);
        acc[0][n] = __builtin_amdgcn_mfma_f32_16x16x32_bf16(qf[0], kf, acc[0][n], 0, 0, 0);
        acc[1][n] = __builtin_amdgcn_mfma_f32_16x16x32_bf16(qf[1], kf, acc[1][n], 0, 0, 0);
    }

    // ---- mask + row max ----
    float rmax[2][4];
    #pragma unroll
    for (int m = 0; m < 2; m++)
        #pragma unroll
        for (int j = 0; j < 4; j++) rmax[m][j] = -3.0e38f;

    #pragma unroll
    for (int n = 0; n < 16; n++) {
        const float madd = mask[(b << 10) + cb + (n << 4) + arow] ? 0.0f : -1e9f;
        #pragma unroll
        for (int m = 0; m < 2; m++)
            #pragma unroll
            for (int j = 0; j < 4; j++) {
                acc[m][n][j] += madd;
                rmax[m][j] = fmaxf(rmax[m][j], acc[m][n][j]);
            }
    }
    #pragma unroll
    for (int off = 1; off < 16; off <<= 1)
        #pragma unroll
        for (int m = 0; m < 2; m++)
            #pragma unroll
            for (int j = 0; j < 4; j++) rmax[m][j] = fmaxf(rmax[m][j], __shfl_xor(rmax[m][j], off));

    if ((lane & 15) == 0) {
        #pragma unroll
        for (int m = 0; m < 2; m++)
            #pragma unroll
            for (int j = 0; j < 4; j++) red[(wid << 5) + (m << 4) + rbase + j] = rmax[m][j];
    }
    __syncthreads();
    #pragma unroll
    for (int m = 0; m < 2; m++)
        #pragma unroll
        for (int j = 0; j < 4; j++) {
            int r = (m << 4) + rbase + j;
            rmax[m][j] = fmaxf(fmaxf(red[r], red[32 + r]), fmaxf(red[64 + r], red[96 + r]));
        }

    // ---- exp + row sum ----
    float rsum[2][4] = {};
    #pragma unroll
    for (int n = 0; n < 16; n++)
        #pragma unroll
        for (int m = 0; m < 2; m++)
            #pragma unroll
            for (int j = 0; j < 4; j++) {
                float p = __expf(acc[m][n][j] - rmax[m][j]);
                acc[m][n][j] = p;
                rsum[m][j] += p;
            }
    #pragma unroll
    for (int off = 1; off < 16; off <<= 1)
        #pragma unroll
        for (int m = 0; m < 2; m++)
            #pragma unroll
            for (int j = 0; j < 4; j++) rsum[m][j] += __shfl_xor(rsum[m][j], off);

    if ((lane & 15) == 0) {
        #pragma unroll
        for (int m = 0; m < 2; m++)
            #pragma unroll
            for (int j = 0; j < 4; j++) red[128 + (wid << 5) + (m << 4) + rbase + j] = rsum[m][j];
    }
    __syncthreads();
    float inv[2][4];
    #pragma unroll
    for (int m = 0; m < 2; m++)
        #pragma unroll
        for (int j = 0; j < 4; j++) {
            int r = 128 + (m << 4) + rbase + j;
            inv[m][j] = 1.0f / (red[r] + red[32 + r] + red[64 + r] + red[96 + r]);
        }
    __syncthreads();   // protect red region before P-tile overwrite

    // ---- normalize: write attn (global f32) + P tile (LDS bf16, XOR-swizzled) ----
    char* ptw = smem + (wid << 14);
    const size_t obase = (((size_t)bh << 10) + q0) << 10;
    #pragma unroll
    for (int m = 0; m < 2; m++)
        #pragma unroll
        for (int j = 0; j < 4; j++) {
            const int qr = (m << 4) + rbase + j;
            float* orow = attn + obase + ((size_t)qr << 10) + cb;
            const float iv = inv[m][j];
            #pragma unroll
            for (int n = 0; n < 16; n++) {
                float p = acc[m][n][j] * iv;
                orow[(n << 4) + arow] = p;
                const int col = (n << 4) + arow;
                *(bf16*)(ptw + (qr << 9) + ((col << 1) ^ ((qr & 7) << 4))) = __float2bfloat16(p);
            }
        }

    // ---- per-wave PV: ctx_partial[32][64] = P_w[32][256] @ V[cb:cb+256][64] ----
    f32x4 acc2[2][4];
    #pragma unroll
    for (int m = 0; m < 2; m++)
        #pragma unroll
        for (int n = 0; n < 4; n++) acc2[m][n] = (f32x4){0.f, 0.f, 0.f, 0.f};

    #pragma unroll
    for (int kk = 0; kk < 8; kk++) {
        short8 af[2];
        #pragma unroll
        for (int m = 0; m < 2; m++)
            af[m] = *(const short8*)(ptw + (((m << 4) + arow) << 9) +
                                     (((kk << 6) + (hi << 4)) ^ ((arow & 7) << 4)));
        #pragma unroll
        for (int n = 0; n < 4; n++) {
            short8 vf = *(const short8*)(vT + ((size_t)((b << 10) + (h << 6) + (n << 4) + arow) << 10) +
                                         cb + (kk << 5) + koff);
            acc2[0][n] = __builtin_amdgcn_mfma_f32_16x16x32_bf16(af[0], vf, acc2[0][n], 0, 0, 0);
            acc2[1][n] = __builtin_amdgcn_mfma_f32_16x16x32_bf16(af[1], vf, acc2[1][n], 0, 0, 0);
        }
    }

    __syncthreads();   // all waves done reading their P tiles
    float* part = (float*)smem;   // [4][32][72]
    #pragma unroll
    for (int m = 0; m < 2; m++)
        #pragma unroll
        for (int n = 0; n < 4; n++)
            #pragma unroll
            for (int j = 0; j < 4; j++)
                part[wid * 2304 + ((m << 4) + rbase + j) * 72 + (n << 4) + arow] = acc2[m][n][j];
    __syncthreads();

    // ---- reduce 4 wave partials, write ctx bf16 ----
    const int qrow = tid >> 3, dkb = (tid & 7) << 3;
    f32x4 sa = (f32x4){0.f, 0.f, 0.f, 0.f}, sb = (f32x4){0.f, 0.f, 0.f, 0.f};
    #pragma unroll
    for (int w = 0; w < 4; w++) {
        const float* p = part + w * 2304 + qrow * 72 + dkb;
        f32x4 a = *(const f32x4*)p;
        f32x4 c = *(const f32x4*)(p + 4);
        sa[0] += a[0]; sa[1] += a[1]; sa[2] += a[2]; sa[3] += a[3];
        sb[0] += c[0]; sb[1] += c[1]; sb[2] += c[2]; sb[3] += c[3];
    }
    short8 o;
    o[0] = f2bf(sa[0]); o[1] = f2bf(sa[1]); o[2] = f2bf(sa[2]); o[3] = f2bf(sa[3]);
    o[4] = f2bf(sb[0]); o[5] = f2bf(sb[1]); o[6] = f2bf(sb[2]); o[7] = f2bf(sb[3]);
    *(short8*)(ctx + ((size_t)((b << 10) + q0 + qrow) << 10) + (h << 6) + dkb) = o;
}

// ---------------------------------------------------------------- launch
extern "C" void kernel_launch(void* const* d_in, const int* in_sizes, int n_in,
                              void* d_out, int out_size, void* d_ws, size_t ws_size,
                              hipStream_t stream) {
    (void)in_sizes; (void)n_in; (void)out_size; (void)ws_size;
    const float* x   = (const float*)d_in[0];
    const int*   mask= (const int*)d_in[1];
    const float* Wq  = (const float*)d_in[2];  const float* bq  = (const float*)d_in[3];
    const float* Wk  = (const float*)d_in[4];  const float* bk  = (const float*)d_in[5];
    const float* Wv  = (const float*)d_in[6];  const float* bv  = (const float*)d_in[7];
    const float* Wo  = (const float*)d_in[8];  const float* bo  = (const float*)d_in[9];
    const float* lag = (const float*)d_in[10]; const float* lab = (const float*)d_in[11];
    const float* W1  = (const float*)d_in[12]; const float* b1  = (const float*)d_in[13];
    const float* W2  = (const float*)d_in[14]; const float* b2  = (const float*)d_in[15];
    const float* lfg = (const float*)d_in[16]; const float* lfb = (const float*)d_in[17];
    const float* bffg= (const float*)d_in[18]; const float* bffb= (const float*)d_in[19];
    const float* bffm= (const float*)d_in[20]; const float* bffv= (const float*)d_in[21];
    const float* b1g = (const float*)d_in[22]; const float* b1b = (const float*)d_in[23];
    const float* b1m = (const float*)d_in[24]; const float* b1v = (const float*)d_in[25];
    const float* b2g = (const float*)d_in[26]; const float* b2b = (const float*)d_in[27];
    const float* b2m = (const float*)d_in[28]; const float* b2v = (const float*)d_in[29];

    char* ws = (char*)d_ws;
    const size_t MB = 1024 * 1024;
    bf16* wqkv_bf = (bf16*)(ws);               // 6 MB  (3072 x 1024)
    bf16* wo_bf   = (bf16*)(ws + 6 * MB);      // 2 MB
    bf16* w1_bf   = (bf16*)(ws + 8 * MB);      // 8 MB
    bf16* w2_bf   = (bf16*)(ws + 16 * MB);     // 8 MB
    float* s1  = (float*)(ws + 24 * MB); float* t1  = s1 + 1024;
    float* s2  = t1 + 1024;              float* t2  = s2 + 1024;
    float* sff = t2 + 1024;              float* tff = sff + 4096;
    bf16* x_bf   = (bf16*)(ws + 25 * MB);
    bf16* xq_bf  = (bf16*)(ws + 41 * MB);
    bf16* q_bf   = (bf16*)(ws + 57 * MB);
    bf16* k_bf   = (bf16*)(ws + 73 * MB);
    bf16* vT_bf  = (bf16*)(ws + 89 * MB);
    bf16* ctx_bf = (bf16*)(ws + 105 * MB);
    float* x1    = (float*)(ws + 121 * MB);    // 32 MB f32
    bf16* xn_bf  = (bf16*)(ws + 153 * MB);
    bf16* h_bf   = (bf16*)(ws + 169 * MB);     // 64 MB, ends at 233 MB

    float* out_x    = (float*)d_out;
    float* out_attn = out_x + (size_t)8 * 1024 * 1024;

    cast_all<<<12288, 256, 0, stream>>>(Wq, Wk, Wv, Wo, W1, W2, wqkv_bf, wo_bf, w1_bf, w2_bf);
    affine_all<<<24, 256, 0, stream>>>(b1g, b1b, b1m, b1v, b2g, b2b, b2m, b2v,
                                       bffg, bffb, bffm, bffv, s1, t1, s2, t2, sff, tff);

    // LN(x) (for q) + raw cast (for k,v)
    ln_kernel<<<8192, 256, 0, stream>>>(x, lag, lab, xq_bf, x_bf);

    // fused q/k/v projection (q scaled by 1/8, v stored transposed)
    gemm_qkv<<<dim3(24, 64), 256, 0, stream>>>(xq_bf, x_bf, wqkv_bf, bq, bk, bv, q_bf, k_bf, vT_bf);

    // fused scores+softmax (-> d_out attn) + PV (-> ctx)
    fattn_kernel<<<dim3(32, 128), 256, 0, stream>>>(q_bf, k_bf, vT_bf, mask, out_attn, ctx_bf);

    // attn_out proj + residual + bn1 -> x1 (f32)
    gemm_kernel<M_RESBN><<<dim3(8, 64), 256, 0, stream>>>(ctx_bf, wo_bf, bo, x1, x, s1, t1, 1024, 1024);

    // FFN: LN -> W1+gelu+bnff -> W2 + residual + bn2 -> d_out
    ln_kernel<<<8192, 256, 0, stream>>>(x1, lfg, lfb, xn_bf, nullptr);
    gemm_kernel<M_GELU><<<dim3(32, 64), 256, 0, stream>>>(xn_bf, w1_bf, b1, h_bf, nullptr, sff, tff, 4096, 1024);
    gemm_kernel<M_RESBN><<<dim3(8, 64), 256, 0, stream>>>(h_bf, w2_bf, b2, out_x, x1, s2, t2, 1024, 4096);
}

// Round 3
// 734.797 us; speedup vs baseline: 1.1223x; 1.0032x over previous
//
#include <hip/hip_runtime.h>
#include <hip/hip_bf16.h>
#include <math.h>

typedef __hip_bfloat16 bf16;
typedef __attribute__((ext_vector_type(8))) short short8;
typedef __attribute__((ext_vector_type(4))) short short4v;
typedef __attribute__((ext_vector_type(4))) float f32x4;

#define DEV static __device__ __forceinline__

DEV short f2bf(float f) {
    bf16 h = __float2bfloat16(f);
    return __builtin_bit_cast(short, h);
}

DEV void glds16(const void* g, void* l) {
    __builtin_amdgcn_global_load_lds((const __attribute__((address_space(1))) void*)g,
                                     (__attribute__((address_space(3))) void*)l, 16, 0, 0);
}

// chunk swizzle hash: row&7 -> 2-bit chunk XOR; spreads a read-quarter's 16 rows
// over all 8 (row parity x chunk) bank groups -> 2 lanes/bank = conflict-free (m136)
DEV int swz(int r7) { return (r7 + (r7 >> 2)) & 3; }

// ---------------------------------------------------------------- all weight casts in one kernel
__global__ __launch_bounds__(256) void cast_all(const float* __restrict__ Wq,
                                                const float* __restrict__ Wk,
                                                const float* __restrict__ Wv,
                                                const float* __restrict__ Wo,
                                                const float* __restrict__ W1,
                                                const float* __restrict__ W2,
                                                bf16* __restrict__ wqkv, bf16* __restrict__ wo,
                                                bf16* __restrict__ w1, bf16* __restrict__ w2) {
    int i = blockIdx.x * 256 + threadIdx.x;
    const float* src;
    bf16* dst;
    int si, di;
    if (i < 786432) {
        src = (i < 262144) ? Wq : (i < 524288) ? Wk : Wv;
        si = (i < 262144) ? i : (i < 524288) ? i - 262144 : i - 524288;
        dst = wqkv; di = i;
    } else if (i < 1048576) {
        src = Wo; si = i - 786432; dst = wo; di = si;
    } else if (i < 2097152) {
        src = W1; si = i - 1048576; dst = w1; di = si;
    } else {
        src = W2; si = i - 2097152; dst = w2; di = si;
    }
    f32x4 v = ((const f32x4*)src)[si];
    short4v o;
    #pragma unroll
    for (int j = 0; j < 4; j++) o[j] = f2bf(v[j]);
    ((short4v*)dst)[di] = o;
}

// ---------------------------------------------------------------- BN eval affines (bn1, bn2, bnff)
__global__ __launch_bounds__(256) void affine_all(
    const float* __restrict__ g1, const float* __restrict__ bb1, const float* __restrict__ m1, const float* __restrict__ v1,
    const float* __restrict__ g2, const float* __restrict__ bb2, const float* __restrict__ m2, const float* __restrict__ v2,
    const float* __restrict__ gf, const float* __restrict__ bbf, const float* __restrict__ mf, const float* __restrict__ vf,
    float* __restrict__ s1, float* __restrict__ t1, float* __restrict__ s2, float* __restrict__ t2,
    float* __restrict__ sf, float* __restrict__ tf) {
    int i = blockIdx.x * 256 + threadIdx.x;
    const float *g, *b, *m, *v; float *s, *t; int j;
    if (i < 1024)      { g = g1; b = bb1; m = m1; v = v1; s = s1; t = t1; j = i; }
    else if (i < 2048) { g = g2; b = bb2; m = m2; v = v2; s = s2; t = t2; j = i - 1024; }
    else               { g = gf; b = bbf; m = mf; v = vf; s = sf; t = tf; j = i - 2048; }
    float sc = g[j] * rsqrtf(v[j] + 1e-5f);
    s[j] = sc;
    t[j] = b[j] - m[j] * sc;
}

// ---------------------------------------------------------------- LayerNorm (row=1024) + optional raw cast
__global__ __launch_bounds__(256) void ln_kernel(const float* __restrict__ x,
                                                 const float* __restrict__ g,
                                                 const float* __restrict__ b,
                                                 bf16* __restrict__ lnout,
                                                 bf16* __restrict__ rawout) {
    const int row = blockIdx.x, t = threadIdx.x;
    const float* xr = x + (size_t)row * 1024;
    f32x4 v = ((const f32x4*)xr)[t];
    float s = v[0] + v[1] + v[2] + v[3];
    float sq = v[0]*v[0] + v[1]*v[1] + v[2]*v[2] + v[3]*v[3];
    #pragma unroll
    for (int off = 1; off < 64; off <<= 1) {
        s  += __shfl_xor(s, off);
        sq += __shfl_xor(sq, off);
    }
    __shared__ float ls[4], lq[4];
    if ((t & 63) == 0) { ls[t >> 6] = s; lq[t >> 6] = sq; }
    __syncthreads();
    s = ls[0] + ls[1] + ls[2] + ls[3];
    sq = lq[0] + lq[1] + lq[2] + lq[3];
    float mu = s * (1.0f / 1024.0f);
    float rs = rsqrtf(sq * (1.0f / 1024.0f) - mu * mu + 1e-5f);
    f32x4 gg = ((const f32x4*)g)[t];
    f32x4 bb = ((const f32x4*)b)[t];
    short4v o;
    #pragma unroll
    for (int j = 0; j < 4; j++) o[j] = f2bf((v[j] - mu) * rs * gg[j] + bb[j]);
    ((short4v*)(lnout + (size_t)row * 1024))[t] = o;
    if (rawout) {
        short4v r;
        #pragma unroll
        for (int j = 0; j < 4; j++) r[j] = f2bf(v[j]);
        ((short4v*)(rawout + (size_t)row * 1024))[t] = r;
    }
}

// ---------------------------------------------------------------- QKV projection: A depends on col region
__global__ __launch_bounds__(256) void gemm_qkv(
    const bf16* __restrict__ Aln, const bf16* __restrict__ Araw, const bf16* __restrict__ Bw,
    const float* __restrict__ bq, const float* __restrict__ bk, const float* __restrict__ bv,
    bf16* __restrict__ qo, bf16* __restrict__ ko, bf16* __restrict__ vTo) {
    __shared__ bf16 As[128 * 32];
    __shared__ bf16 Bs[128 * 32];
    const int tid = threadIdx.x, lane = tid & 63, wid = tid >> 6;
    const int bm = blockIdx.y << 7, bn = blockIdx.x << 7;
    const bf16* A = (bn < 1024) ? Aln : Araw;
    const int wm = (wid >> 1) << 6, wn = (wid & 1) << 6;
    f32x4 acc[4][4] = {};
    const int strow = (wid << 4) + (lane >> 2);
    const int stcol = (((lane & 3) ^ swz((lane >> 2) & 7)) << 3);   // swizzled source chunk
    const bf16* ag0 = A + (size_t)(bm + strow) * 1024 + stcol;
    const bf16* ag1 = A + (size_t)(bm + 64 + strow) * 1024 + stcol;
    const bf16* bg0 = Bw + (size_t)(bn + strow) * 1024 + stcol;
    const bf16* bg1 = Bw + (size_t)(bn + 64 + strow) * 1024 + stcol;
    bf16* la0 = As + (wid << 9);
    bf16* la1 = As + 2048 + (wid << 9);
    bf16* lb0 = Bs + (wid << 9);
    bf16* lb1 = Bs + 2048 + (wid << 9);
    const int arow = lane & 15;
    const int koff = ((lane >> 4) ^ swz(arow & 7)) << 3;            // swizzled read chunk

    for (int kb = 0; kb < 1024; kb += 32) {
        glds16(ag0 + kb, la0);
        glds16(ag1 + kb, la1);
        glds16(bg0 + kb, lb0);
        glds16(bg1 + kb, lb1);
        __syncthreads();
        short8 af[4], bfr[4];
        #pragma unroll
        for (int m = 0; m < 4; m++)
            af[m] = *(const short8*)(As + ((wm + (m << 4) + arow) << 5) + koff);
        #pragma unroll
        for (int n = 0; n < 4; n++)
            bfr[n] = *(const short8*)(Bs + ((wn + (n << 4) + arow) << 5) + koff);
        #pragma unroll
        for (int m = 0; m < 4; m++)
            #pragma unroll
            for (int n = 0; n < 4; n++)
                acc[m][n] = __builtin_amdgcn_mfma_f32_16x16x32_bf16(af[m], bfr[n], acc[m][n], 0, 0, 0);
        __syncthreads();
    }

    #pragma unroll
    for (int m = 0; m < 4; m++) {
        #pragma unroll
        for (int n = 0; n < 4; n++) {
            const int col = bn + wn + (n << 4) + arow;
            const int reg = col >> 10, c = col & 1023;
            const float bvv = (reg == 0) ? bq[c] : (reg == 1) ? bk[c] : bv[c];
            #pragma unroll
            for (int j = 0; j < 4; j++) {
                const int row = bm + wm + (m << 4) + ((lane >> 4) << 2) + j;
                float v = acc[m][n][j] + bvv;
                if (reg == 0)
                    qo[(size_t)row * 1024 + c] = __float2bfloat16(v * 0.125f);
                else if (reg == 1)
                    ko[(size_t)row * 1024 + c] = __float2bfloat16(v);
                else
                    vTo[((size_t)(row >> 10) << 20) + ((size_t)c << 10) + (row & 1023)] =
                        __float2bfloat16(v);
            }
        }
    }
}

// ---------------------------------------------------------------- generic GEMM epilogues
enum { M_RESBN = 0, M_GELU = 1 };

template <int MODE>
__global__ __launch_bounds__(256) void gemm_kernel(
    const bf16* __restrict__ A, const bf16* __restrict__ Bw, const float* __restrict__ bias,
    void* __restrict__ out, const float* __restrict__ res,
    const float* __restrict__ sa, const float* __restrict__ ta,
    int N, int K) {
    __shared__ bf16 As[128 * 32];
    __shared__ bf16 Bs[128 * 32];
    const int tid = threadIdx.x, lane = tid & 63, wid = tid >> 6;
    const int bm = blockIdx.y << 7, bn = blockIdx.x << 7;
    const int wm = (wid >> 1) << 6, wn = (wid & 1) << 6;
    f32x4 acc[4][4] = {};
    const int strow = (wid << 4) + (lane >> 2);
    const int stcol = (((lane & 3) ^ swz((lane >> 2) & 7)) << 3);   // swizzled source chunk
    const bf16* ag0 = A + (size_t)(bm + strow) * K + stcol;
    const bf16* ag1 = A + (size_t)(bm + 64 + strow) * K + stcol;
    const bf16* bg0 = Bw + (size_t)(bn + strow) * K + stcol;
    const bf16* bg1 = Bw + (size_t)(bn + 64 + strow) * K + stcol;
    bf16* la0 = As + (wid << 9);
    bf16* la1 = As + 2048 + (wid << 9);
    bf16* lb0 = Bs + (wid << 9);
    bf16* lb1 = Bs + 2048 + (wid << 9);
    const int arow = lane & 15;
    const int koff = ((lane >> 4) ^ swz(arow & 7)) << 3;            // swizzled read chunk

    for (int kb = 0; kb < K; kb += 32) {
        glds16(ag0 + kb, la0);
        glds16(ag1 + kb, la1);
        glds16(bg0 + kb, lb0);
        glds16(bg1 + kb, lb1);
        __syncthreads();
        short8 af[4], bfr[4];
        #pragma unroll
        for (int m = 0; m < 4; m++)
            af[m] = *(const short8*)(As + ((wm + (m << 4) + arow) << 5) + koff);
        #pragma unroll
        for (int n = 0; n < 4; n++)
            bfr[n] = *(const short8*)(Bs + ((wn + (n << 4) + arow) << 5) + koff);
        #pragma unroll
        for (int m = 0; m < 4; m++)
            #pragma unroll
            for (int n = 0; n < 4; n++)
                acc[m][n] = __builtin_amdgcn_mfma_f32_16x16x32_bf16(af[m], bfr[n], acc[m][n], 0, 0, 0);
        __syncthreads();
    }

    #pragma unroll
    for (int m = 0; m < 4; m++) {
        #pragma unroll
        for (int n = 0; n < 4; n++) {
            const int col = bn + wn + (n << 4) + arow;
            const float bv = bias[col];
            #pragma unroll
            for (int j = 0; j < 4; j++) {
                const int row = bm + wm + (m << 4) + ((lane >> 4) << 2) + j;
                float v = acc[m][n][j] + bv;
                if constexpr (MODE == M_RESBN) {
                    size_t idx = (size_t)row * N + col;
                    ((float*)out)[idx] = (res[idx] + v) * sa[col] + ta[col];
                } else {  // M_GELU
                    float ge = 0.5f * v * (1.0f + erff(v * 0.70710678118f));
                    ((bf16*)out)[(size_t)row * N + col] = __float2bfloat16(ge * sa[col] + ta[col]);
                }
            }
        }
    }
}

// ---------------------------------------------------------------- fused scores+softmax+attn-write+PV
__global__ __launch_bounds__(256) void fattn_kernel(const bf16* __restrict__ q,
                                                    const bf16* __restrict__ k,
                                                    const bf16* __restrict__ vT,
                                                    const int* __restrict__ mask,
                                                    float* __restrict__ attn,
                                                    bf16* __restrict__ ctx) {
    const int bh = blockIdx.y, b = bh >> 4, h = bh & 15;
    const int q0 = blockIdx.x << 5;
    const int tid = threadIdx.x, lane = tid & 63, wid = tid >> 6;
    const int cb = wid << 8;
    const int arow = lane & 15, hi = lane >> 4, koff = hi << 3;
    const int rbase = hi << 2;

    __shared__ char smem[65536];
    float* red = (float*)smem;   // [2][4][32]

    // ---- QK^T ----
    short8 qf[2];
    #pragma unroll
    for (int m = 0; m < 2; m++)
        qf[m] = *(const short8*)(q + ((size_t)((b << 10) + q0 + (m << 4) + arow) << 10) + (h << 6) + koff);

    f32x4 acc[2][16];
    #pragma unroll
    for (int m = 0; m < 2; m++)
        #pragma unroll
        for (int n = 0; n < 16; n++) acc[m][n] = (f32x4){0.f, 0.f, 0.f, 0.f};

    #pragma unroll
    for (int n = 0; n < 16; n++) {
        short8 kf = *(const short8*)(k + ((size_t)((b << 10) + cb + (n << 4) + arow) << 10) + (h << 6) + koff);
        acc[0][n] = __builtin_amdgcn_mfma_f32_16x16x32_bf16(qf[0], kf, acc[0][n], 0, 0, 0);
        acc[1][n] = __builtin_amdgcn_mfma_f32_16x16x32_bf16(qf[1], kf, acc[1][n], 0, 0, 0);
    }

    // ---- mask + row max ----
    float rmax[2][4];
    #pragma unroll
    for (int m = 0; m < 2; m++)
        #pragma unroll
        for (int j = 0; j < 4; j++) rmax[m][j] = -3.0e38f;

    #pragma unroll
    for (int n = 0; n < 16; n++) {
        const float madd = mask[(b << 10) + cb + (n << 4) + arow] ? 0.0f : -1e9f;
        #pragma unroll
        for (int m = 0; m < 2; m++)
            #pragma unroll
            for (int j = 0; j < 4; j++) {
                acc[m][n][j] += madd;
                rmax[m][j] = fmaxf(rmax[m][j], acc[m][n][j]);
            }
    }
    #pragma unroll
    for (int off = 1; off < 16; off <<= 1)
        #pragma unroll
        for (int m = 0; m < 2; m++)
            #pragma unroll
            for (int j = 0; j < 4; j++) rmax[m][j] = fmaxf(rmax[m][j], __shfl_xor(rmax[m][j], off));

    if ((lane & 15) == 0) {
        #pragma unroll
        for (int m = 0; m < 2; m++)
            #pragma unroll
            for (int j = 0; j < 4; j++) red[(wid << 5) + (m << 4) + rbase + j] = rmax[m][j];
    }
    __syncthreads();
    #pragma unroll
    for (int m = 0; m < 2; m++)
        #pragma unroll
        for (int j = 0; j < 4; j++) {
            int r = (m << 4) + rbase + j;
            rmax[m][j] = fmaxf(fmaxf(red[r], red[32 + r]), fmaxf(red[64 + r], red[96 + r]));
        }

    // ---- exp + row sum ----
    float rsum[2][4] = {};
    #pragma unroll
    for (int n = 0; n < 16; n++)
        #pragma unroll
        for (int m = 0; m < 2; m++)
            #pragma unroll
            for (int j = 0; j < 4; j++) {
                float p = __expf(acc[m][n][j] - rmax[m][j]);
                acc[m][n][j] = p;
                rsum[m][j] += p;
            }
    #pragma unroll
    for (int off = 1; off < 16; off <<= 1)
        #pragma unroll
        for (int m = 0; m < 2; m++)
            #pragma unroll
            for (int j = 0; j < 4; j++) rsum[m][j] += __shfl_xor(rsum[m][j], off);

    if ((lane & 15) == 0) {
        #pragma unroll
        for (int m = 0; m < 2; m++)
            #pragma unroll
            for (int j = 0; j < 4; j++) red[128 + (wid << 5) + (m << 4) + rbase + j] = rsum[m][j];
    }
    __syncthreads();
    float inv[2][4];
    #pragma unroll
    for (int m = 0; m < 2; m++)
        #pragma unroll
        for (int j = 0; j < 4; j++) {
            int r = 128 + (m << 4) + rbase + j;
            inv[m][j] = 1.0f / (red[r] + red[32 + r] + red[64 + r] + red[96 + r]);
        }
    __syncthreads();   // protect red region before P-tile overwrite

    // ---- normalize: write attn (global f32) + P tile (LDS bf16, XOR-swizzled) ----
    char* ptw = smem + (wid << 14);
    const size_t obase = (((size_t)bh << 10) + q0) << 10;
    #pragma unroll
    for (int m = 0; m < 2; m++)
        #pragma unroll
        for (int j = 0; j < 4; j++) {
            const int qr = (m << 4) + rbase + j;
            float* orow = attn + obase + ((size_t)qr << 10) + cb;
            const float iv = inv[m][j];
            #pragma unroll
            for (int n = 0; n < 16; n++) {
                float p = acc[m][n][j] * iv;
                orow[(n << 4) + arow] = p;
                const int col = (n << 4) + arow;
                *(bf16*)(ptw + (qr << 9) + ((col << 1) ^ ((qr & 7) << 4))) = __float2bfloat16(p);
            }
        }

    // ---- per-wave PV: ctx_partial[32][64] = P_w[32][256] @ V[cb:cb+256][64] ----
    f32x4 acc2[2][4];
    #pragma unroll
    for (int m = 0; m < 2; m++)
        #pragma unroll
        for (int n = 0; n < 4; n++) acc2[m][n] = (f32x4){0.f, 0.f, 0.f, 0.f};

    #pragma unroll
    for (int kk = 0; kk < 8; kk++) {
        short8 af[2];
        #pragma unroll
        for (int m = 0; m < 2; m++)
            af[m] = *(const short8*)(ptw + (((m << 4) + arow) << 9) +
                                     (((kk << 6) + (hi << 4)) ^ ((arow & 7) << 4)));
        #pragma unroll
        for (int n = 0; n < 4; n++) {
            short8 vf = *(const short8*)(vT + ((size_t)((b << 10) + (h << 6) + (n << 4) + arow) << 10) +
                                         cb + (kk << 5) + koff);
            acc2[0][n] = __builtin_amdgcn_mfma_f32_16x16x32_bf16(af[0], vf, acc2[0][n], 0, 0, 0);
            acc2[1][n] = __builtin_amdgcn_mfma_f32_16x16x32_bf16(af[1], vf, acc2[1][n], 0, 0, 0);
        }
    }

    __syncthreads();   // all waves done reading their P tiles
    float* part = (float*)smem;   // [4][32][72]
    #pragma unroll
    for (int m = 0; m < 2; m++)
        #pragma unroll
        for (int n = 0; n < 4; n++)
            #pragma unroll
            for (int j = 0; j < 4; j++)
                part[wid * 2304 + ((m << 4) + rbase + j) * 72 + (n << 4) + arow] = acc2[m][n][j];
    __syncthreads();

    // ---- reduce 4 wave partials, write ctx bf16 ----
    const int qrow = tid >> 3, dkb = (tid & 7) << 3;
    f32x4 sa = (f32x4){0.f, 0.f, 0.f, 0.f}, sb = (f32x4){0.f, 0.f, 0.f, 0.f};
    #pragma unroll
    for (int w = 0; w < 4; w++) {
        const float* p = part + w * 2304 + qrow * 72 + dkb;
        f32x4 a = *(const f32x4*)p;
        f32x4 c = *(const f32x4*)(p + 4);
        sa[0] += a[0]; sa[1] += a[1]; sa[2] += a[2]; sa[3] += a[3];
        sb[0] += c[0]; sb[1] += c[1]; sb[2] += c[2]; sb[3] += c[3];
    }
    short8 o;
    o[0] = f2bf(sa[0]); o[1] = f2bf(sa[1]); o[2] = f2bf(sa[2]); o[3] = f2bf(sa[3]);
    o[4] = f2bf(sb[0]); o[5] = f2bf(sb[1]); o[6] = f2bf(sb[2]); o[7] = f2bf(sb[3]);
    *(short8*)(ctx + ((size_t)((b << 10) + q0 + qrow) << 10) + (h << 6) + dkb) = o;
}

// ---------------------------------------------------------------- launch
extern "C" void kernel_launch(void* const* d_in, const int* in_sizes, int n_in,
                              void* d_out, int out_size, void* d_ws, size_t ws_size,
                              hipStream_t stream) {
    (void)in_sizes; (void)n_in; (void)out_size; (void)ws_size;
    const float* x   = (const float*)d_in[0];
    const int*   mask= (const int*)d_in[1];
    const float* Wq  = (const float*)d_in[2];  const float* bq  = (const float*)d_in[3];
    const float* Wk  = (const float*)d_in[4];  const float* bk  = (const float*)d_in[5];
    const float* Wv  = (const float*)d_in[6];  const float* bv  = (const float*)d_in[7];
    const float* Wo  = (const float*)d_in[8];  const float* bo  = (const float*)d_in[9];
    const float* lag = (const float*)d_in[10]; const float* lab = (const float*)d_in[11];
    const float* W1  = (const float*)d_in[12]; const float* b1  = (const float*)d_in[13];
    const float* W2  = (const float*)d_in[14]; const float* b2  = (const float*)d_in[15];
    const float* lfg = (const float*)d_in[16]; const float* lfb = (const float*)d_in[17];
    const float* bffg= (const float*)d_in[18]; const float* bffb= (const float*)d_in[19];
    const float* bffm= (const float*)d_in[20]; const float* bffv= (const float*)d_in[21];
    const float* b1g = (const float*)d_in[22]; const float* b1b = (const float*)d_in[23];
    const float* b1m = (const float*)d_in[24]; const float* b1v = (const float*)d_in[25];
    const float* b2g = (const float*)d_in[26]; const float* b2b = (const float*)d_in[27];
    const float* b2m = (const float*)d_in[28]; const float* b2v = (const float*)d_in[29];

    char* ws = (char*)d_ws;
    const size_t MB = 1024 * 1024;
    bf16* wqkv_bf = (bf16*)(ws);               // 6 MB  (3072 x 1024)
    bf16* wo_bf   = (bf16*)(ws + 6 * MB);      // 2 MB
    bf16* w1_bf   = (bf16*)(ws + 8 * MB);      // 8 MB
    bf16* w2_bf   = (bf16*)(ws + 16 * MB);     // 8 MB
    float* s1  = (float*)(ws + 24 * MB); float* t1  = s1 + 1024;
    float* s2  = t1 + 1024;              float* t2  = s2 + 1024;
    float* sff = t2 + 1024;              float* tff = sff + 4096;
    bf16* x_bf   = (bf16*)(ws + 25 * MB);
    bf16* xq_bf  = (bf16*)(ws + 41 * MB);
    bf16* q_bf   = (bf16*)(ws + 57 * MB);
    bf16* k_bf   = (bf16*)(ws + 73 * MB);
    bf16* vT_bf  = (bf16*)(ws + 89 * MB);
    bf16* ctx_bf = (bf16*)(ws + 105 * MB);
    float* x1    = (float*)(ws + 121 * MB);    // 32 MB f32
    bf16* xn_bf  = (bf16*)(ws + 153 * MB);
    bf16* h_bf   = (bf16*)(ws + 169 * MB);     // 64 MB, ends at 233 MB

    float* out_x    = (float*)d_out;
    float* out_attn = out_x + (size_t)8 * 1024 * 1024;

    cast_all<<<12288, 256, 0, stream>>>(Wq, Wk, Wv, Wo, W1, W2, wqkv_bf, wo_bf, w1_bf, w2_bf);
    affine_all<<<24, 256, 0, stream>>>(b1g, b1b, b1m, b1v, b2g, b2b, b2m, b2v,
                                       bffg, bffb, bffm, bffv, s1, t1, s2, t2, sff, tff);

    // LN(x) (for q) + raw cast (for k,v)
    ln_kernel<<<8192, 256, 0, stream>>>(x, lag, lab, xq_bf, x_bf);

    // fused q/k/v projection (q scaled by 1/8, v stored transposed)
    gemm_qkv<<<dim3(24, 64), 256, 0, stream>>>(xq_bf, x_bf, wqkv_bf, bq, bk, bv, q_bf, k_bf, vT_bf);

    // fused scores+softmax (-> d_out attn) + PV (-> ctx)
    fattn_kernel<<<dim3(32, 128), 256, 0, stream>>>(q_bf, k_bf, vT_bf, mask, out_attn, ctx_bf);

    // attn_out proj + residual + bn1 -> x1 (f32)
    gemm_kernel<M_RESBN><<<dim3(8, 64), 256, 0, stream>>>(ctx_bf, wo_bf, bo, x1, x, s1, t1, 1024, 1024);

    // FFN: LN -> W1+gelu+bnff -> W2 + residual + bn2 -> d_out
    ln_kernel<<<8192, 256, 0, stream>>>(x1, lfg, lfb, xn_bf, nullptr);
    gemm_kernel<M_GELU><<<dim3(32, 64), 256, 0, stream>>>(xn_bf, w1_bf, b1, h_bf, nullptr, sff, tff, 4096, 1024);
    gemm_kernel<M_RESBN><<<dim3(8, 64), 256, 0, stream>>>(h_bf, w2_bf, b2, out_x, x1, s2, t2, 1024, 4096);
}

// Round 4
// 713.789 us; speedup vs baseline: 1.1553x; 1.0294x over previous
//
#include <hip/hip_runtime.h>
#include <hip/hip_bf16.h>
#include <math.h>

typedef __hip_bfloat16 bf16;
typedef __attribute__((ext_vector_type(8))) short short8;
typedef __attribute__((ext_vector_type(4))) short short4v;
typedef __attribute__((ext_vector_type(4))) float f32x4;

#define DEV static __device__ __forceinline__

DEV short f2bf(float f) {
    bf16 h = __float2bfloat16(f);
    return __builtin_bit_cast(short, h);
}

DEV void glds16(const void* g, void* l) {
    __builtin_amdgcn_global_load_lds((const __attribute__((address_space(1))) void*)g,
                                     (__attribute__((address_space(3))) void*)l, 16, 0, 0);
}

// chunk swizzle hash: maps (row&7) -> 2-bit chunk XOR; spreads a read-quarter's
// 16 rows over all 8 (row-parity x chunk) bank groups -> 2 lanes/bank (free, m136)
DEV int swz(int r7) { return (r7 + (r7 >> 2)) & 3; }

// ---------------------------------------------------------------- all weight casts in one kernel
__global__ __launch_bounds__(256) void cast_all(const float* __restrict__ Wq,
                                                const float* __restrict__ Wk,
                                                const float* __restrict__ Wv,
                                                const float* __restrict__ Wo,
                                                const float* __restrict__ W1,
                                                const float* __restrict__ W2,
                                                bf16* __restrict__ wqkv, bf16* __restrict__ wo,
                                                bf16* __restrict__ w1, bf16* __restrict__ w2) {
    int i = blockIdx.x * 256 + threadIdx.x;
    const float* src;
    bf16* dst;
    int si, di;
    if (i < 786432) {
        src = (i < 262144) ? Wq : (i < 524288) ? Wk : Wv;
        si = (i < 262144) ? i : (i < 524288) ? i - 262144 : i - 524288;
        dst = wqkv; di = i;
    } else if (i < 1048576) {
        src = Wo; si = i - 786432; dst = wo; di = si;
    } else if (i < 2097152) {
        src = W1; si = i - 1048576; dst = w1; di = si;
    } else {
        src = W2; si = i - 2097152; dst = w2; di = si;
    }
    f32x4 v = ((const f32x4*)src)[si];
    short4v o;
    #pragma unroll
    for (int j = 0; j < 4; j++) o[j] = f2bf(v[j]);
    ((short4v*)dst)[di] = o;
}

// ---------------------------------------------------------------- BN eval affines (bn1, bn2, bnff)
__global__ __launch_bounds__(256) void affine_all(
    const float* __restrict__ g1, const float* __restrict__ bb1, const float* __restrict__ m1, const float* __restrict__ v1,
    const float* __restrict__ g2, const float* __restrict__ bb2, const float* __restrict__ m2, const float* __restrict__ v2,
    const float* __restrict__ gf, const float* __restrict__ bbf, const float* __restrict__ mf, const float* __restrict__ vf,
    float* __restrict__ s1, float* __restrict__ t1, float* __restrict__ s2, float* __restrict__ t2,
    float* __restrict__ sf, float* __restrict__ tf) {
    int i = blockIdx.x * 256 + threadIdx.x;
    const float *g, *b, *m, *v; float *s, *t; int j;
    if (i < 1024)      { g = g1; b = bb1; m = m1; v = v1; s = s1; t = t1; j = i; }
    else if (i < 2048) { g = g2; b = bb2; m = m2; v = v2; s = s2; t = t2; j = i - 1024; }
    else               { g = gf; b = bbf; m = mf; v = vf; s = sf; t = tf; j = i - 2048; }
    float sc = g[j] * rsqrtf(v[j] + 1e-5f);
    s[j] = sc;
    t[j] = b[j] - m[j] * sc;
}

// ---------------------------------------------------------------- LayerNorm (row=1024) + optional raw cast
__global__ __launch_bounds__(256) void ln_kernel(const float* __restrict__ x,
                                                 const float* __restrict__ g,
                                                 const float* __restrict__ b,
                                                 bf16* __restrict__ lnout,
                                                 bf16* __restrict__ rawout) {
    const int row = blockIdx.x, t = threadIdx.x;
    const float* xr = x + (size_t)row * 1024;
    f32x4 v = ((const f32x4*)xr)[t];
    float s = v[0] + v[1] + v[2] + v[3];
    float sq = v[0]*v[0] + v[1]*v[1] + v[2]*v[2] + v[3]*v[3];
    #pragma unroll
    for (int off = 1; off < 64; off <<= 1) {
        s  += __shfl_xor(s, off);
        sq += __shfl_xor(sq, off);
    }
    __shared__ float ls[4], lq[4];
    if ((t & 63) == 0) { ls[t >> 6] = s; lq[t >> 6] = sq; }
    __syncthreads();
    s = ls[0] + ls[1] + ls[2] + ls[3];
    sq = lq[0] + lq[1] + lq[2] + lq[3];
    float mu = s * (1.0f / 1024.0f);
    float rs = rsqrtf(sq * (1.0f / 1024.0f) - mu * mu + 1e-5f);
    f32x4 gg = ((const f32x4*)g)[t];
    f32x4 bb = ((const f32x4*)b)[t];
    short4v o;
    #pragma unroll
    for (int j = 0; j < 4; j++) o[j] = f2bf((v[j] - mu) * rs * gg[j] + bb[j]);
    ((short4v*)(lnout + (size_t)row * 1024))[t] = o;
    if (rawout) {
        short4v r;
        #pragma unroll
        for (int j = 0; j < 4; j++) r[j] = f2bf(v[j]);
        ((short4v*)(rawout + (size_t)row * 1024))[t] = r;
    }
}

// ================================================================ pipelined GEMM engine
// C = A[M,K] @ B[N,K]^T. 256 x BN tile, BK=32, 8 waves, 4-slot LDS ring, depth-3
// prefetch with counted vmcnt (never 0 in steady state) + raw s_barrier.
enum { M_RESBN = 0, M_GELU = 1 };

template <int BN, int MODE>
__global__ __launch_bounds__(512, 2) void gemm3(
    const bf16* __restrict__ A, const bf16* __restrict__ Bw, const float* __restrict__ bias,
    void* __restrict__ out, const float* __restrict__ res,
    const float* __restrict__ sa, const float* __restrict__ ta,
    int N, int K) {
    constexpr int WR = (BN == 256) ? 2 : 4;    // wave grid rows
    constexpr int WC = (BN == 256) ? 4 : 2;    // wave grid cols
    constexpr int RW = 256 / WR;               // wave-tile rows
    constexpr int CW = BN / WC;                // wave-tile cols (64)
    constexpr int MF = RW / 16;                // 8 or 4
    constexpr int NF = CW / 16;                // 4
    constexpr int LB = BN / 128;               // B-stage issues (2 or 1)
    constexpr int SLOT_B = BN * 64;            // bytes per B slot
    __shared__ char smem[65536 + 4 * SLOT_B];

    const int tid = threadIdx.x, lane = tid & 63, wid = tid >> 6;
    const int wr = wid / WC, wc = wid % WC;
    const int bm = blockIdx.y << 8, bn = blockIdx.x * BN;
    const int arow = lane & 15, hi = lane >> 4;
    const int koff = (hi ^ swz(arow & 7)) << 3;
    f32x4 acc[MF][NF] = {};

    auto stage = [&](int T) {
        const int kb = T << 5;
        const int slot = T & 3;
        #pragma unroll
        for (int i = 0; i < 2; i++) {
            const int idx = i * 512 + tid;
            const int r = idx >> 2, cc = idx & 3;
            glds16(A + (size_t)(bm + r) * K + kb + ((cc ^ swz(r & 7)) << 3),
                   smem + slot * 16384 + i * 8192 + wid * 1024);
        }
        #pragma unroll
        for (int i = 0; i < LB; i++) {
            const int idx = i * 512 + tid;
            const int r = idx >> 2, cc = idx & 3;
            glds16(Bw + (size_t)(bn + r) * K + kb + ((cc ^ swz(r & 7)) << 3),
                   smem + 65536 + slot * SLOT_B + i * 8192 + wid * 1024);
        }
    };

    const int NT = K >> 5;
    stage(0); stage(1); stage(2);
    for (int T = 0; T < NT; T++) {
        // counted drain: tile T's loads retired; tiles T+1,T+2 stay in flight
        if (T < NT - 2) {
            if constexpr (BN == 256) asm volatile("s_waitcnt vmcnt(8)" ::: "memory");
            else                     asm volatile("s_waitcnt vmcnt(6)" ::: "memory");
        } else if (T == NT - 2) {
            if constexpr (BN == 256) asm volatile("s_waitcnt vmcnt(4)" ::: "memory");
            else                     asm volatile("s_waitcnt vmcnt(3)" ::: "memory");
        } else {
            asm volatile("s_waitcnt vmcnt(0)" ::: "memory");
        }
        __builtin_amdgcn_s_barrier();          // NOT __syncthreads(): avoid forced vmcnt(0)
        if (T + 3 < NT) stage(T + 3);          // slot (T+3)&3 freed: last read in tile T-1
        const int slot = T & 3;
        const bf16* As = (const bf16*)(smem + slot * 16384);
        const bf16* Bs = (const bf16*)(smem + 65536 + slot * SLOT_B);
        short8 af[MF], bv[NF];
        #pragma unroll
        for (int mf = 0; mf < MF; mf++)
            af[mf] = *(const short8*)(As + ((wr * RW + mf * 16 + arow) << 5) + koff);
        #pragma unroll
        for (int nf = 0; nf < NF; nf++)
            bv[nf] = *(const short8*)(Bs + ((wc * CW + nf * 16 + arow) << 5) + koff);
        __builtin_amdgcn_s_setprio(1);
        #pragma unroll
        for (int mf = 0; mf < MF; mf++)
            #pragma unroll
            for (int nf = 0; nf < NF; nf++)
                acc[mf][nf] = __builtin_amdgcn_mfma_f32_16x16x32_bf16(af[mf], bv[nf], acc[mf][nf], 0, 0, 0);
        __builtin_amdgcn_s_setprio(0);
    }

    #pragma unroll
    for (int mf = 0; mf < MF; mf++) {
        #pragma unroll
        for (int nf = 0; nf < NF; nf++) {
            const int col = bn + wc * CW + nf * 16 + arow;
            const float bvv = bias[col];
            #pragma unroll
            for (int j = 0; j < 4; j++) {
                const int row = bm + wr * RW + mf * 16 + hi * 4 + j;
                float v = acc[mf][nf][j] + bvv;
                if constexpr (MODE == M_RESBN) {
                    size_t idx = (size_t)row * N + col;
                    ((float*)out)[idx] = (res[idx] + v) * sa[col] + ta[col];
                } else {  // M_GELU
                    float ge = 0.5f * v * (1.0f + erff(v * 0.70710678118f));
                    ((bf16*)out)[(size_t)row * N + col] = __float2bfloat16(ge * sa[col] + ta[col]);
                }
            }
        }
    }
}

// ---------------------------------------------------------------- QKV projection on the same engine (BN=128)
__global__ __launch_bounds__(512, 2) void gemm_qkv3(
    const bf16* __restrict__ Aln, const bf16* __restrict__ Araw, const bf16* __restrict__ Bw,
    const float* __restrict__ bq, const float* __restrict__ bk, const float* __restrict__ bv,
    bf16* __restrict__ qo, bf16* __restrict__ ko, bf16* __restrict__ vTo) {
    constexpr int BN = 128, WC = 2, RW = 64, CW = 64, MF = 4, NF = 4, SLOT_B = 8192;
    constexpr int K = 1024;
    __shared__ char smem[65536 + 4 * SLOT_B];

    const int tid = threadIdx.x, lane = tid & 63, wid = tid >> 6;
    const int wr = wid / WC, wc = wid % WC;
    const int bm = blockIdx.y << 8, bn = blockIdx.x * BN;
    const bf16* A = (bn < 1024) ? Aln : Araw;
    const int arow = lane & 15, hi = lane >> 4;
    const int koff = (hi ^ swz(arow & 7)) << 3;
    f32x4 acc[MF][NF] = {};

    auto stage = [&](int T) {
        const int kb = T << 5;
        const int slot = T & 3;
        #pragma unroll
        for (int i = 0; i < 2; i++) {
            const int idx = i * 512 + tid;
            const int r = idx >> 2, cc = idx & 3;
            glds16(A + (size_t)(bm + r) * K + kb + ((cc ^ swz(r & 7)) << 3),
                   smem + slot * 16384 + i * 8192 + wid * 1024);
        }
        {
            const int idx = tid;
            const int r = idx >> 2, cc = idx & 3;
            glds16(Bw + (size_t)(bn + r) * K + kb + ((cc ^ swz(r & 7)) << 3),
                   smem + 65536 + slot * SLOT_B + wid * 1024);
        }
    };

    const int NT = K >> 5;   // 32
    stage(0); stage(1); stage(2);
    for (int T = 0; T < NT; T++) {
        if (T < NT - 2)       asm volatile("s_waitcnt vmcnt(6)" ::: "memory");
        else if (T == NT - 2) asm volatile("s_waitcnt vmcnt(3)" ::: "memory");
        else                  asm volatile("s_waitcnt vmcnt(0)" ::: "memory");
        __builtin_amdgcn_s_barrier();
        if (T + 3 < NT) stage(T + 3);
        const int slot = T & 3;
        const bf16* As = (const bf16*)(smem + slot * 16384);
        const bf16* Bs = (const bf16*)(smem + 65536 + slot * SLOT_B);
        short8 af[MF], bvv[NF];
        #pragma unroll
        for (int mf = 0; mf < MF; mf++)
            af[mf] = *(const short8*)(As + ((wr * RW + mf * 16 + arow) << 5) + koff);
        #pragma unroll
        for (int nf = 0; nf < NF; nf++)
            bvv[nf] = *(const short8*)(Bs + ((wc * CW + nf * 16 + arow) << 5) + koff);
        __builtin_amdgcn_s_setprio(1);
        #pragma unroll
        for (int mf = 0; mf < MF; mf++)
            #pragma unroll
            for (int nf = 0; nf < NF; nf++)
                acc[mf][nf] = __builtin_amdgcn_mfma_f32_16x16x32_bf16(af[mf], bvv[nf], acc[mf][nf], 0, 0, 0);
        __builtin_amdgcn_s_setprio(0);
    }

    #pragma unroll
    for (int mf = 0; mf < MF; mf++) {
        #pragma unroll
        for (int nf = 0; nf < NF; nf++) {
            const int col = bn + wc * CW + nf * 16 + arow;
            const int reg = col >> 10, c = col & 1023;
            const float bb = (reg == 0) ? bq[c] : (reg == 1) ? bk[c] : bv[c];
            #pragma unroll
            for (int j = 0; j < 4; j++) {
                const int row = bm + wr * RW + mf * 16 + hi * 4 + j;
                float v = acc[mf][nf][j] + bb;
                if (reg == 0)
                    qo[(size_t)row * 1024 + c] = __float2bfloat16(v * 0.125f);
                else if (reg == 1)
                    ko[(size_t)row * 1024 + c] = __float2bfloat16(v);
                else
                    vTo[((size_t)(row >> 10) << 20) + ((size_t)c << 10) + (row & 1023)] =
                        __float2bfloat16(v);
            }
        }
    }
}

// ---------------------------------------------------------------- fused scores+softmax+attn-write+PV
__global__ __launch_bounds__(256) void fattn_kernel(const bf16* __restrict__ q,
                                                    const bf16* __restrict__ k,
                                                    const bf16* __restrict__ vT,
                                                    const int* __restrict__ mask,
                                                    float* __restrict__ attn,
                                                    bf16* __restrict__ ctx) {
    const int bh = blockIdx.y, b = bh >> 4, h = bh & 15;
    const int q0 = blockIdx.x << 5;
    const int tid = threadIdx.x, lane = tid & 63, wid = tid >> 6;
    const int cb = wid << 8;
    const int arow = lane & 15, hi = lane >> 4, koff = hi << 3;
    const int rbase = hi << 2;

    __shared__ char smem[65536];
    float* red = (float*)smem;   // [2][4][32]

    // ---- QK^T ----
    short8 qf[2];
    #pragma unroll
    for (int m = 0; m < 2; m++)
        qf[m] = *(const short8*)(q + ((size_t)((b << 10) + q0 + (m << 4) + arow) << 10) + (h << 6) + koff);

    f32x4 acc[2][16];
    #pragma unroll
    for (int m = 0; m < 2; m++)
        #pragma unroll
        for (int n = 0; n < 16; n++) acc[m][n] = (f32x4){0.f, 0.f, 0.f, 0.f};

    #pragma unroll
    for (int n = 0; n < 16; n++) {
        short8 kf = *(const short8*)(k + ((size_t)((b << 10) + cb + (n << 4) + arow) << 10) + (h << 6) + koff);
        acc[0][n] = __builtin_amdgcn_mfma_f32_16x16x32_bf16(qf[0], kf, acc[0][n], 0, 0, 0);
        acc[1][n] = __builtin_amdgcn_mfma_f32_16x16x32_bf16(qf[1], kf, acc[1][n], 0, 0, 0);
    }

    // ---- mask + row max ----
    float rmax[2][4];
    #pragma unroll
    for (int m = 0; m < 2; m++)
        #pragma unroll
        for (int j = 0; j < 4; j++) rmax[m][j] = -3.0e38f;

    #pragma unroll
    for (int n = 0; n < 16; n++) {
        const float madd = mask[(b << 10) + cb + (n << 4) + arow] ? 0.0f : -1e9f;
        #pragma unroll
        for (int m = 0; m < 2; m++)
            #pragma unroll
            for (int j = 0; j < 4; j++) {
                acc[m][n][j] += madd;
                rmax[m][j] = fmaxf(rmax[m][j], acc[m][n][j]);
            }
    }
    #pragma unroll
    for (int off = 1; off < 16; off <<= 1)
        #pragma unroll
        for (int m = 0; m < 2; m++)
            #pragma unroll
            for (int j = 0; j < 4; j++) rmax[m][j] = fmaxf(rmax[m][j], __shfl_xor(rmax[m][j], off));

    if ((lane & 15) == 0) {
        #pragma unroll
        for (int m = 0; m < 2; m++)
            #pragma unroll
            for (int j = 0; j < 4; j++) red[(wid << 5) + (m << 4) + rbase + j] = rmax[m][j];
    }
    __syncthreads();
    #pragma unroll
    for (int m = 0; m < 2; m++)
        #pragma unroll
        for (int j = 0; j < 4; j++) {
            int r = (m << 4) + rbase + j;
            rmax[m][j] = fmaxf(fmaxf(red[r], red[32 + r]), fmaxf(red[64 + r], red[96 + r]));
        }

    // ---- exp + row sum ----
    float rsum[2][4] = {};
    #pragma unroll
    for (int n = 0; n < 16; n++)
        #pragma unroll
        for (int m = 0; m < 2; m++)
            #pragma unroll
            for (int j = 0; j < 4; j++) {
                float p = __expf(acc[m][n][j] - rmax[m][j]);
                acc[m][n][j] = p;
                rsum[m][j] += p;
            }
    #pragma unroll
    for (int off = 1; off < 16; off <<= 1)
        #pragma unroll
        for (int m = 0; m < 2; m++)
            #pragma unroll
            for (int j = 0; j < 4; j++) rsum[m][j] += __shfl_xor(rsum[m][j], off);

    if ((lane & 15) == 0) {
        #pragma unroll
        for (int m = 0; m < 2; m++)
            #pragma unroll
            for (int j = 0; j < 4; j++) red[128 + (wid << 5) + (m << 4) + rbase + j] = rsum[m][j];
    }
    __syncthreads();
    float inv[2][4];
    #pragma unroll
    for (int m = 0; m < 2; m++)
        #pragma unroll
        for (int j = 0; j < 4; j++) {
            int r = 128 + (m << 4) + rbase + j;
            inv[m][j] = 1.0f / (red[r] + red[32 + r] + red[64 + r] + red[96 + r]);
        }
    __syncthreads();   // protect red region before P-tile overwrite

    // ---- normalize: write attn (global f32) + P tile (LDS bf16, XOR-swizzled) ----
    char* ptw = smem + (wid << 14);
    const size_t obase = (((size_t)bh << 10) + q0) << 10;
    #pragma unroll
    for (int m = 0; m < 2; m++)
        #pragma unroll
        for (int j = 0; j < 4; j++) {
            const int qr = (m << 4) + rbase + j;
            float* orow = attn + obase + ((size_t)qr << 10) + cb;
            const float iv = inv[m][j];
            #pragma unroll
            for (int n = 0; n < 16; n++) {
                float p = acc[m][n][j] * iv;
                orow[(n << 4) + arow] = p;
                const int col = (n << 4) + arow;
                *(bf16*)(ptw + (qr << 9) + ((col << 1) ^ ((qr & 7) << 4))) = __float2bfloat16(p);
            }
        }

    // ---- per-wave PV: ctx_partial[32][64] = P_w[32][256] @ V[cb:cb+256][64] ----
    f32x4 acc2[2][4];
    #pragma unroll
    for (int m = 0; m < 2; m++)
        #pragma unroll
        for (int n = 0; n < 4; n++) acc2[m][n] = (f32x4){0.f, 0.f, 0.f, 0.f};

    #pragma unroll
    for (int kk = 0; kk < 8; kk++) {
        short8 af[2];
        #pragma unroll
        for (int m = 0; m < 2; m++)
            af[m] = *(const short8*)(ptw + (((m << 4) + arow) << 9) +
                                     (((kk << 6) + (hi << 4)) ^ ((arow & 7) << 4)));
        #pragma unroll
        for (int n = 0; n < 4; n++) {
            short8 vf = *(const short8*)(vT + ((size_t)((b << 10) + (h << 6) + (n << 4) + arow) << 10) +
                                         cb + (kk << 5) + koff);
            acc2[0][n] = __builtin_amdgcn_mfma_f32_16x16x32_bf16(af[0], vf, acc2[0][n], 0, 0, 0);
            acc2[1][n] = __builtin_amdgcn_mfma_f32_16x16x32_bf16(af[1], vf, acc2[1][n], 0, 0, 0);
        }
    }

    __syncthreads();   // all waves done reading their P tiles
    float* part = (float*)smem;   // [4][32][72]
    #pragma unroll
    for (int m = 0; m < 2; m++)
        #pragma unroll
        for (int n = 0; n < 4; n++)
            #pragma unroll
            for (int j = 0; j < 4; j++)
                part[wid * 2304 + ((m << 4) + rbase + j) * 72 + (n << 4) + arow] = acc2[m][n][j];
    __syncthreads();

    // ---- reduce 4 wave partials, write ctx bf16 ----
    const int qrow = tid >> 3, dkb = (tid & 7) << 3;
    f32x4 sa = (f32x4){0.f, 0.f, 0.f, 0.f}, sb = (f32x4){0.f, 0.f, 0.f, 0.f};
    #pragma unroll
    for (int w = 0; w < 4; w++) {
        const float* p = part + w * 2304 + qrow * 72 + dkb;
        f32x4 a = *(const f32x4*)p;
        f32x4 c = *(const f32x4*)(p + 4);
        sa[0] += a[0]; sa[1] += a[1]; sa[2] += a[2]; sa[3] += a[3];
        sb[0] += c[0]; sb[1] += c[1]; sb[2] += c[2]; sb[3] += c[3];
    }
    short8 o;
    o[0] = f2bf(sa[0]); o[1] = f2bf(sa[1]); o[2] = f2bf(sa[2]); o[3] = f2bf(sa[3]);
    o[4] = f2bf(sb[0]); o[5] = f2bf(sb[1]); o[6] = f2bf(sb[2]); o[7] = f2bf(sb[3]);
    *(short8*)(ctx + ((size_t)((b << 10) + q0 + qrow) << 10) + (h << 6) + dkb) = o;
}

// ---------------------------------------------------------------- launch
extern "C" void kernel_launch(void* const* d_in, const int* in_sizes, int n_in,
                              void* d_out, int out_size, void* d_ws, size_t ws_size,
                              hipStream_t stream) {
    (void)in_sizes; (void)n_in; (void)out_size; (void)ws_size;
    const float* x   = (const float*)d_in[0];
    const int*   mask= (const int*)d_in[1];
    const float* Wq  = (const float*)d_in[2];  const float* bq  = (const float*)d_in[3];
    const float* Wk  = (const float*)d_in[4];  const float* bk  = (const float*)d_in[5];
    const float* Wv  = (const float*)d_in[6];  const float* bv  = (const float*)d_in[7];
    const float* Wo  = (const float*)d_in[8];  const float* bo  = (const float*)d_in[9];
    const float* lag = (const float*)d_in[10]; const float* lab = (const float*)d_in[11];
    const float* W1  = (const float*)d_in[12]; const float* b1  = (const float*)d_in[13];
    const float* W2  = (const float*)d_in[14]; const float* b2  = (const float*)d_in[15];
    const float* lfg = (const float*)d_in[16]; const float* lfb = (const float*)d_in[17];
    const float* bffg= (const float*)d_in[18]; const float* bffb= (const float*)d_in[19];
    const float* bffm= (const float*)d_in[20]; const float* bffv= (const float*)d_in[21];
    const float* b1g = (const float*)d_in[22]; const float* b1b = (const float*)d_in[23];
    const float* b1m = (const float*)d_in[24]; const float* b1v = (const float*)d_in[25];
    const float* b2g = (const float*)d_in[26]; const float* b2b = (const float*)d_in[27];
    const float* b2m = (const float*)d_in[28]; const float* b2v = (const float*)d_in[29];

    char* ws = (char*)d_ws;
    const size_t MB = 1024 * 1024;
    bf16* wqkv_bf = (bf16*)(ws);               // 6 MB  (3072 x 1024)
    bf16* wo_bf   = (bf16*)(ws + 6 * MB);      // 2 MB
    bf16* w1_bf   = (bf16*)(ws + 8 * MB);      // 8 MB
    bf16* w2_bf   = (bf16*)(ws + 16 * MB);     // 8 MB
    float* s1  = (float*)(ws + 24 * MB); float* t1  = s1 + 1024;
    float* s2  = t1 + 1024;              float* t2  = s2 + 1024;
    float* sff = t2 + 1024;              float* tff = sff + 4096;
    bf16* x_bf   = (bf16*)(ws + 25 * MB);
    bf16* xq_bf  = (bf16*)(ws + 41 * MB);
    bf16* q_bf   = (bf16*)(ws + 57 * MB);
    bf16* k_bf   = (bf16*)(ws + 73 * MB);
    bf16* vT_bf  = (bf16*)(ws + 89 * MB);
    bf16* ctx_bf = (bf16*)(ws + 105 * MB);
    float* x1    = (float*)(ws + 121 * MB);    // 32 MB f32
    bf16* xn_bf  = (bf16*)(ws + 153 * MB);
    bf16* h_bf   = (bf16*)(ws + 169 * MB);     // 64 MB, ends at 233 MB

    float* out_x    = (float*)d_out;
    float* out_attn = out_x + (size_t)8 * 1024 * 1024;

    cast_all<<<12288, 256, 0, stream>>>(Wq, Wk, Wv, Wo, W1, W2, wqkv_bf, wo_bf, w1_bf, w2_bf);
    affine_all<<<24, 256, 0, stream>>>(b1g, b1b, b1m, b1v, b2g, b2b, b2m, b2v,
                                       bffg, bffb, bffm, bffv, s1, t1, s2, t2, sff, tff);

    // LN(x) (for q) + raw cast (for k,v)
    ln_kernel<<<8192, 256, 0, stream>>>(x, lag, lab, xq_bf, x_bf);

    // fused q/k/v projection (q scaled by 1/8, v stored transposed)
    gemm_qkv3<<<dim3(24, 32), 512, 0, stream>>>(xq_bf, x_bf, wqkv_bf, bq, bk, bv, q_bf, k_bf, vT_bf);

    // fused scores+softmax (-> d_out attn) + PV (-> ctx)
    fattn_kernel<<<dim3(32, 128), 256, 0, stream>>>(q_bf, k_bf, vT_bf, mask, out_attn, ctx_bf);

    // attn_out proj + residual + bn1 -> x1 (f32)
    gemm3<128, M_RESBN><<<dim3(8, 32), 512, 0, stream>>>(ctx_bf, wo_bf, bo, x1, x, s1, t1, 1024, 1024);

    // FFN: LN -> W1+gelu+bnff -> W2 + residual + bn2 -> d_out
    ln_kernel<<<8192, 256, 0, stream>>>(x1, lfg, lfb, xn_bf, nullptr);
    gemm3<256, M_GELU><<<dim3(16, 32), 512, 0, stream>>>(xn_bf, w1_bf, b1, h_bf, nullptr, sff, tff, 4096, 1024);
    gemm3<128, M_RESBN><<<dim3(8, 32), 512, 0, stream>>>(h_bf, w2_bf, b2, out_x, x1, s2, t2, 1024, 4096);
}